// Round 1
// baseline (473.104 us; speedup 1.0000x reference)
//
#include <hip/hip_runtime.h>
#include <stdint.h>

#define NN 36864        // 192*192 spatial
#define PL 7077888      // 192*NN  per-batch full-C plane
#define PL64 2359296    // 64*NN
#define TOT 14155776    // 2*192*NN elements per output tensor

typedef unsigned short ushort_t;
typedef __attribute__((ext_vector_type(8))) __bf16 bf16x8;
typedef __attribute__((ext_vector_type(4))) float f32x4;
typedef __attribute__((ext_vector_type(4))) unsigned int u32x4;

__device__ __forceinline__ ushort_t f2bf(float f) {
  unsigned int u = __builtin_bit_cast(unsigned int, f);
  u = (u + 0x7FFFu + ((u >> 16) & 1u)) >> 16;   // RNE
  return (ushort_t)u;
}
__device__ __forceinline__ float bf2f(ushort_t h) {
  unsigned int u = ((unsigned int)h) << 16;
  return __builtin_bit_cast(float, u);
}
__device__ __forceinline__ bf16x8 lds8(const ushort_t* p) {
  return __builtin_bit_cast(bf16x8, *(const u32x4*)p);
}
__device__ __forceinline__ f32x4 mfma16(bf16x8 a, bf16x8 b, f32x4 c) {
  return __builtin_amdgcn_mfma_f32_16x16x32_bf16(a, b, c, 0, 0, 0);
}

// ---------------- weight prep: Wstack = [wq*lnw ; wv] bf16, alpha/beta ----------------
__global__ void k_prep(const float* __restrict__ wq, const float* __restrict__ wv,
                       const float* __restrict__ lnw, const float* __restrict__ lnb,
                       ushort_t* __restrict__ W, float* __restrict__ ab) {
  __shared__ float sa[3], sb[3];
  int r = blockIdx.x, t = threadIdx.x;   // 384 blocks x 192 threads
  if (r < 192) {
    float w  = wq[r*192 + t];
    float lw = lnw[t], lb = lnb[t];
    W[r*192 + t] = f2bf(w * lw);
    float av = w * lb, bv = -w * lw;
    #pragma unroll
    for (int off = 1; off < 64; off <<= 1) {
      av += __shfl_xor(av, off);
      bv += __shfl_xor(bv, off);
    }
    if ((t & 63) == 0) { sa[t >> 6] = av; sb[t >> 6] = bv; }
    __syncthreads();
    if (t == 0) { ab[r] = sa[0]+sa[1]+sa[2]; ab[192 + r] = sb[0]+sb[1]+sb[2]; }
  } else {
    W[r*192 + t] = f2bf(wv[(r-192)*192 + t]);
  }
}

// ---------------- LN stats over channel dim ----------------
__global__ void k_stats(const float* __restrict__ xl, const float* __restrict__ xr,
                        float* __restrict__ stl, float* __restrict__ str) {
  int bid = blockIdx.x;                  // 576 = 2 sides * 2 b * 144
  int side = bid / 288, rem = bid % 288;
  int b = rem / 144, nb = rem % 144;
  const float* x = side ? xr : xl;
  float* st = side ? str : stl;
  int n = nb*256 + threadIdx.x;
  const float* p = x + (size_t)b*PL + n;
  float s = 0.f, s2 = 0.f;
  #pragma unroll 4
  for (int c = 0; c < 192; ++c) { float v = p[(size_t)c*NN]; s += v; s2 += v*v; }
  float mu = s * (1.f/192.f);
  float var = s2 * (1.f/192.f) - mu*mu;
  st[(b*2+0)*NN + n] = mu;
  st[(b*2+1)*NN + n] = rsqrtf(var + 1e-6f);
}

// ---------------- projection GEMM: [384x192]bf16 @ [192x64]x : q(fixup)+v ----------------
__global__ __launch_bounds__(256, 2) void k_proj(
    const float* __restrict__ xl, const float* __restrict__ xr,
    const ushort_t* __restrict__ Wl, const ushort_t* __restrict__ Wr,
    const float* __restrict__ abl, const float* __restrict__ abr,
    const float* __restrict__ stl, const float* __restrict__ str,
    ushort_t* __restrict__ Ql, ushort_t* __restrict__ Qr,
    ushort_t* __restrict__ Vl, ushort_t* __restrict__ Vr,
    float* __restrict__ gap) {
  __shared__ ushort_t As[384*32];
  __shared__ ushort_t Bs[64*32];
  const int side = blockIdx.y;
  const float*    x  = side ? xr  : xl;
  const ushort_t* W  = side ? Wr  : Wl;
  const float*    ab = side ? abr : abl;
  const float*    st = side ? str : stl;
  ushort_t* Q = side ? Qr : Ql;
  ushort_t* V = side ? Vr : Vl;
  const int b  = blockIdx.x / 576;
  const int n0 = (blockIdx.x % 576) * 64;
  const int tid = threadIdx.x;
  const int wave = tid >> 6, lane = tid & 63, lr = lane & 15, lg = lane >> 4;

  const f32x4 fz = {0.f, 0.f, 0.f, 0.f};
  f32x4 acc[6][4];
  #pragma unroll
  for (int mf = 0; mf < 6; ++mf) {
    #pragma unroll
    for (int nf = 0; nf < 4; ++nf) acc[mf][nf] = fz;
  }

  const int sn = tid & 63, skb = tid >> 6;
  for (int ks = 0; ks < 6; ++ks) {
    const int k0 = ks * 32;
    #pragma unroll
    for (int i = 0; i < 6; ++i) {         // A tile: 384x32 bf16 (swizzled 16B slots)
      int idx = tid + 256*i;
      int m = idx >> 2, kb = idx & 3;
      *(u32x4*)&As[m*32 + 8*(kb ^ ((m>>1)&3))] = *(const u32x4*)&W[m*192 + k0 + kb*8];
    }
    {                                      // B tile: x fp32 -> bf16, [n][k] layout
      const float* xp = x + (size_t)b*PL + (size_t)(k0 + skb*8)*NN + n0 + sn;
      union { ushort_t us[8]; u32x4 v; } tu;
      #pragma unroll
      for (int j = 0; j < 8; ++j) tu.us[j] = f2bf(xp[(size_t)j*NN]);
      *(u32x4*)&Bs[sn*32 + 8*(skb ^ ((sn>>1)&3))] = tu.v;
    }
    __syncthreads();
    bf16x8 bfr[4];
    #pragma unroll
    for (int nf = 0; nf < 4; ++nf) {
      int n_ = nf*16 + lr;
      bfr[nf] = lds8(&Bs[n_*32 + 8*(lg ^ ((n_>>1)&3))]);
    }
    #pragma unroll
    for (int mf = 0; mf < 6; ++mf) {
      int m_ = wave*96 + mf*16 + lr;
      bf16x8 af = lds8(&As[m_*32 + 8*(lg ^ ((m_>>1)&3))]);
      #pragma unroll
      for (int nf = 0; nf < 4; ++nf) acc[mf][nf] = mfma16(af, bfr[nf], acc[mf][nf]);
    }
    __syncthreads();
  }

  float rst[4], mrs[4];
  if (wave < 2) {
    #pragma unroll
    for (int nf = 0; nf < 4; ++nf) {
      int n_ = n0 + nf*16 + lr;
      float rs = st[(b*2+1)*NN + n_];
      rst[nf] = rs;
      mrs[nf] = st[(b*2+0)*NN + n_] * rs;
    }
  }
  #pragma unroll
  for (int mf = 0; mf < 6; ++mf) {
    #pragma unroll
    for (int i = 0; i < 4; ++i) {
      int m = wave*96 + mf*16 + lg*4 + i;   // uniform per (wave,mf): boundaries on 16-multiples
      if (m < 128) {                        // q_h / q_w -> store with LN fixup
        float a_ = ab[m], b_ = ab[192 + m];
        #pragma unroll
        for (int nf = 0; nf < 4; ++nf) {
          float q = acc[mf][nf][i]*rst[nf] + b_*mrs[nf] + a_;
          Q[(size_t)(b*128 + m)*NN + n0 + nf*16 + lr] = f2bf(q);
        }
      } else if (m < 192) {                 // q_c -> GAP partial only
        float a_ = ab[m], b_ = ab[192 + m];
        float part = 0.f;
        #pragma unroll
        for (int nf = 0; nf < 4; ++nf) part += acc[mf][nf][i]*rst[nf] + b_*mrs[nf] + a_;
        #pragma unroll
        for (int off = 1; off < 16; off <<= 1) part += __shfl_xor(part, off);
        if (lr == 0) atomicAdd(&gap[b*64 + (m - 128)], part);
      } else {                              // v -> store raw
        #pragma unroll
        for (int nf = 0; nf < 4; ++nf)
          V[(size_t)(b*192 + (m - 192))*NN + n0 + nf*16 + lr] = f2bf(acc[mf][nf][i]);
      }
    }
  }
}

// ---------------- repack q_h -> [b][w][h][c], q_w -> [b][h][w][c] ----------------
__global__ void k_repack_q(const ushort_t* __restrict__ Ql, const ushort_t* __restrict__ Qr,
                           ushort_t* __restrict__ qhTl, ushort_t* __restrict__ qhTr,
                           ushort_t* __restrict__ qwTl, ushort_t* __restrict__ qwTr) {
  __shared__ ushort_t Ls[64*72];
  int which = blockIdx.y;                 // 0 qhT_l 1 qhT_r 2 qwT_l 3 qwT_r
  const ushort_t* Q = (which & 1) ? Qr : Ql;
  ushort_t* out = which==0 ? qhTl : which==1 ? qhTr : which==2 ? qwTl : qwTr;
  int coff = (which >= 2) ? 64 : 0;
  int bx = blockIdx.x;                    // 1152 = 2b * 192h * 3wtiles
  int b = bx / 576, rem = bx % 576;
  int h = rem / 3, w0 = (rem % 3) * 64;
  int tid = threadIdx.x;
  #pragma unroll
  for (int i = 0; i < 2; ++i) {
    int idx = tid + 256*i;
    int c = idx >> 3, wb = idx & 7;
    *(u32x4*)&Ls[c*72 + wb*8] =
      *(const u32x4*)&Q[(size_t)(b*128 + coff + c)*NN + h*192 + w0 + wb*8];
  }
  __syncthreads();
  #pragma unroll
  for (int i = 0; i < 2; ++i) {
    int idx = tid + 256*i;
    int w = idx >> 3, cb = idx & 7;
    union { ushort_t us[8]; u32x4 v; } tu;
    #pragma unroll
    for (int j = 0; j < 8; ++j) tu.us[j] = Ls[(cb*8+j)*72 + w];
    size_t o;
    if (which < 2) o = ((size_t)(b*192 + w0 + w)*192 + h)*64 + cb*8;
    else           o = ((size_t)(b*192 + h)*192 + w0 + w)*64 + cb*8;
    *(u32x4*)&out[o] = tu.v;
  }
}

// ---------------- repack v_h (ch 0..63 of V): [b][c][h][w] -> [b][c][w][h] ----------------
__global__ void k_repack_v(const ushort_t* __restrict__ Vl, const ushort_t* __restrict__ Vr,
                           ushort_t* __restrict__ vhTl, ushort_t* __restrict__ vhTr) {
  __shared__ ushort_t Ls[64*72];
  const ushort_t* V = blockIdx.y ? Vr : Vl;
  ushort_t* out = blockIdx.y ? vhTr : vhTl;
  int bx = blockIdx.x;                    // 1152 = 2b * 64c * 9 tiles
  int b = bx / 576, rem = bx % 576;
  int c = rem / 9, tt = rem % 9;
  int h0 = (tt/3)*64, w0 = (tt%3)*64;
  int tid = threadIdx.x;
  #pragma unroll
  for (int i = 0; i < 2; ++i) {
    int idx = tid + 256*i;
    int hh = idx >> 3, wb = idx & 7;
    *(u32x4*)&Ls[hh*72 + wb*8] =
      *(const u32x4*)&V[(size_t)(b*192 + c)*NN + (h0+hh)*192 + w0 + wb*8];
  }
  __syncthreads();
  #pragma unroll
  for (int i = 0; i < 2; ++i) {
    int idx = tid + 256*i;
    int ww = idx >> 3, hb = idx & 7;
    union { ushort_t us[8]; u32x4 v; } tu;
    #pragma unroll
    for (int j = 0; j < 8; ++j) tu.us[j] = Ls[(hb*8+j)*72 + ww];
    *(u32x4*)&out[(size_t)(b*64 + c)*NN + (w0+ww)*192 + h0 + hb*8] = tu.v;
  }
}

// ---------------- axial attention, MODE 0 = height (T layouts), 1 = width ----------------
template<int MODE>
__global__ __launch_bounds__(256, 1) void k_attn(
    const ushort_t* __restrict__ qTl, const ushort_t* __restrict__ qTr,
    const ushort_t* __restrict__ Vlp, const ushort_t* __restrict__ Vrp,
    const float* __restrict__ scale_p,
    ushort_t* __restrict__ O1p, ushort_t* __restrict__ O2p) {
  __shared__ ushort_t Qsl[192*72];   // [spatial][c] pad72
  __shared__ ushort_t Qsr[192*72];
  __shared__ ushort_t Pls[192*200];  // P[col][row]
  __shared__ ushort_t Vs[64*200];    // [c][spatial] pad200
  __shared__ float md[192*2];

  const int tid = threadIdx.x;
  const int wave = tid >> 6, lane = tid & 63, lr = lane & 15, lg = lane >> 4;
  const int b = blockIdx.x / 192, s0 = blockIdx.x % 192;
  const float scl = scale_p[0];
  const f32x4 fz = {0.f, 0.f, 0.f, 0.f};

  const ushort_t* ql = qTl + (size_t)(b*192 + s0)*12288;
  const ushort_t* qr = qTr + (size_t)(b*192 + s0)*12288;
  const ushort_t* vr = MODE ? Vrp + (size_t)(b*192 + 64)*NN + s0*192
                            : Vrp + (size_t)b*PL64 + s0*192;
  const ushort_t* vl = MODE ? Vlp + (size_t)(b*192 + 64)*NN + s0*192
                            : Vlp + (size_t)b*PL64 + s0*192;
  ushort_t* o1 = O1p + (size_t)b*PL64 + s0*192;
  ushort_t* o2 = O2p + (size_t)b*PL64 + s0*192;

  #pragma unroll
  for (int i = 0; i < 6; ++i) {           // stage Q tiles + V_r
    int idx = tid + 256*i;
    int h = idx >> 3, cb = idx & 7;
    *(u32x4*)&Qsl[h*72 + cb*8] = *(const u32x4*)&ql[h*64 + cb*8];
    *(u32x4*)&Qsr[h*72 + cb*8] = *(const u32x4*)&qr[h*64 + cb*8];
    int c = idx / 24, gb = idx % 24;
    *(u32x4*)&Vs[c*200 + gb*8] = *(const u32x4*)&vr[(size_t)c*NN + gb*8];
  }
  __syncthreads();

  f32x4 acc[12][3];
  #pragma unroll
  for (int mf = 0; mf < 12; ++mf) {
    #pragma unroll
    for (int nf = 0; nf < 3; ++nf) acc[mf][nf] = fz;
  }
  // pass1: S^T frags (rows = softmax axis, cols = this wave's 48 of the other axis)
  #pragma unroll
  for (int kh = 0; kh < 2; ++kh) {
    const int k0 = kh * 32;
    bf16x8 bq[3];
    #pragma unroll
    for (int nf = 0; nf < 3; ++nf) {
      int n_ = wave*48 + nf*16 + lr;
      bq[nf] = lds8(&Qsl[n_*72 + k0 + lg*8]);
    }
    #pragma unroll
    for (int mf = 0; mf < 12; ++mf) {
      bf16x8 aq = lds8(&Qsr[(mf*16 + lr)*72 + k0 + lg*8]);
      #pragma unroll
      for (int nf = 0; nf < 3; ++nf) acc[mf][nf] = mfma16(aq, bq[nf], acc[mf][nf]);
    }
  }
  // softmax over rows per column; store (max,den) for H pass2
  #pragma unroll
  for (int nf = 0; nf < 3; ++nf) {
    float mx = -3.4e38f;
    #pragma unroll
    for (int mf = 0; mf < 12; ++mf) {
      #pragma unroll
      for (int i = 0; i < 4; ++i) {
        float v = acc[mf][nf][i] * scl;
        acc[mf][nf][i] = v;
        mx = fmaxf(mx, v);
      }
    }
    mx = fmaxf(mx, __shfl_xor(mx, 16));
    mx = fmaxf(mx, __shfl_xor(mx, 32));
    float den = 0.f;
    #pragma unroll
    for (int mf = 0; mf < 12; ++mf) {
      #pragma unroll
      for (int i = 0; i < 4; ++i) {
        float e = __expf(acc[mf][nf][i] - mx);
        acc[mf][nf][i] = e;
        den += e;
      }
    }
    den += __shfl_xor(den, 16);
    den += __shfl_xor(den, 32);
    int col = wave*48 + nf*16 + lr;
    if (lg == 0) { md[col*2] = mx; md[col*2+1] = den; }
    float rd = 1.f / den;
    #pragma unroll
    for (int mf = 0; mf < 12; ++mf) {
      #pragma unroll
      for (int i = 0; i < 4; ++i)
        Pls[col*200 + mf*16 + lg*4 + i] = f2bf(acc[mf][nf][i] * rd);
    }
  }
  __syncthreads();

  {                                        // O1 = V_r x P1
    f32x4 o[4][3];
    #pragma unroll
    for (int mf = 0; mf < 4; ++mf) {
      #pragma unroll
      for (int nf = 0; nf < 3; ++nf) o[mf][nf] = fz;
    }
    #pragma unroll
    for (int ks = 0; ks < 6; ++ks) {
      int k0 = ks * 32;
      bf16x8 bp[3];
      #pragma unroll
      for (int nf = 0; nf < 3; ++nf) {
        int n_ = wave*48 + nf*16 + lr;
        bp[nf] = lds8(&Pls[n_*200 + k0 + lg*8]);
      }
      #pragma unroll
      for (int mf = 0; mf < 4; ++mf) {
        bf16x8 av = lds8(&Vs[(mf*16 + lr)*200 + k0 + lg*8]);
        #pragma unroll
        for (int nf = 0; nf < 3; ++nf) o[mf][nf] = mfma16(av, bp[nf], o[mf][nf]);
      }
    }
    #pragma unroll
    for (int mf = 0; mf < 4; ++mf) {
      #pragma unroll
      for (int i = 0; i < 4; ++i) {
        #pragma unroll
        for (int nf = 0; nf < 3; ++nf)
          o1[(size_t)(mf*16 + lg*4 + i)*NN + wave*48 + nf*16 + lr] = f2bf(o[mf][nf][i]);
      }
    }
  }
  __syncthreads();

  #pragma unroll
  for (int i = 0; i < 6; ++i) {            // stage V_l over Vs
    int idx = tid + 256*i;
    int c = idx / 24, gb = idx % 24;
    *(u32x4*)&Vs[c*200 + gb*8] = *(const u32x4*)&vl[(size_t)c*NN + gb*8];
  }

  // pass2: S frags with swapped roles
  #pragma unroll
  for (int mf = 0; mf < 12; ++mf) {
    #pragma unroll
    for (int nf = 0; nf < 3; ++nf) acc[mf][nf] = fz;
  }
  #pragma unroll
  for (int kh = 0; kh < 2; ++kh) {
    const int k0 = kh * 32;
    bf16x8 bq[3];
    #pragma unroll
    for (int nf = 0; nf < 3; ++nf) {
      int n_ = wave*48 + nf*16 + lr;
      bq[nf] = lds8(&Qsr[n_*72 + k0 + lg*8]);
    }
    #pragma unroll
    for (int mf = 0; mf < 12; ++mf) {
      bf16x8 aq = lds8(&Qsl[(mf*16 + lr)*72 + k0 + lg*8]);
      #pragma unroll
      for (int nf = 0; nf < 3; ++nf) acc[mf][nf] = mfma16(aq, bq[nf], acc[mf][nf]);
    }
  }
  if (MODE == 0) {                         // H: reuse softmax stats keyed by row h
    #pragma unroll
    for (int mf = 0; mf < 12; ++mf) {
      #pragma unroll
      for (int i = 0; i < 4; ++i) {
        int row = mf*16 + lg*4 + i;
        float mx = md[row*2];
        float rd = 1.f / md[row*2+1];
        #pragma unroll
        for (int nf = 0; nf < 3; ++nf) {
          int col = wave*48 + nf*16 + lr;
          Pls[col*200 + row] = f2bf(__expf(acc[mf][nf][i]*scl - mx) * rd);
        }
      }
    }
  } else {                                 // W: independent second softmax (over w, per v)
    #pragma unroll
    for (int nf = 0; nf < 3; ++nf) {
      float mx = -3.4e38f;
      #pragma unroll
      for (int mf = 0; mf < 12; ++mf) {
        #pragma unroll
        for (int i = 0; i < 4; ++i) {
          float v = acc[mf][nf][i] * scl;
          acc[mf][nf][i] = v;
          mx = fmaxf(mx, v);
        }
      }
      mx = fmaxf(mx, __shfl_xor(mx, 16));
      mx = fmaxf(mx, __shfl_xor(mx, 32));
      float den = 0.f;
      #pragma unroll
      for (int mf = 0; mf < 12; ++mf) {
        #pragma unroll
        for (int i = 0; i < 4; ++i) {
          float e = __expf(acc[mf][nf][i] - mx);
          acc[mf][nf][i] = e;
          den += e;
        }
      }
      den += __shfl_xor(den, 16);
      den += __shfl_xor(den, 32);
      int col = wave*48 + nf*16 + lr;
      float rd = 1.f / den;
      #pragma unroll
      for (int mf = 0; mf < 12; ++mf) {
        #pragma unroll
        for (int i = 0; i < 4; ++i)
          Pls[col*200 + mf*16 + lg*4 + i] = f2bf(acc[mf][nf][i] * rd);
      }
    }
  }
  __syncthreads();

  {                                        // O2 = V_l x P2
    f32x4 o[4][3];
    #pragma unroll
    for (int mf = 0; mf < 4; ++mf) {
      #pragma unroll
      for (int nf = 0; nf < 3; ++nf) o[mf][nf] = fz;
    }
    #pragma unroll
    for (int ks = 0; ks < 6; ++ks) {
      int k0 = ks * 32;
      bf16x8 bp[3];
      #pragma unroll
      for (int nf = 0; nf < 3; ++nf) {
        int n_ = wave*48 + nf*16 + lr;
        bp[nf] = lds8(&Pls[n_*200 + k0 + lg*8]);
      }
      #pragma unroll
      for (int mf = 0; mf < 4; ++mf) {
        bf16x8 av = lds8(&Vs[(mf*16 + lr)*200 + k0 + lg*8]);
        #pragma unroll
        for (int nf = 0; nf < 3; ++nf) o[mf][nf] = mfma16(av, bp[nf], o[mf][nf]);
      }
    }
    #pragma unroll
    for (int mf = 0; mf < 4; ++mf) {
      #pragma unroll
      for (int i = 0; i < 4; ++i) {
        #pragma unroll
        for (int nf = 0; nf < 3; ++nf)
          o2[(size_t)(mf*16 + lg*4 + i)*NN + wave*48 + nf*16 + lr] = f2bf(o[mf][nf][i]);
      }
    }
  }
}

// ---------------- SE MLP ----------------
__global__ void k_se(const float* __restrict__ gap, const float* __restrict__ w1,
                     const float* __restrict__ w2, float* __restrict__ sea) {
  __shared__ float p[2][64];
  __shared__ float h1[2][8];
  __shared__ float lgt[2][128];
  __shared__ float mred[2], dred[2];
  int t = threadIdx.x;
  if (t < 128) p[t>>6][t&63] = gap[t] * (1.f/36864.f);
  __syncthreads();
  if (t < 16) {
    int bb = t >> 3, j = t & 7;
    float s = 0.f;
    for (int k = 0; k < 64; ++k) s += p[bb][k] * w1[j*64 + k];
    h1[bb][j] = fmaxf(s, 0.f);
  }
  __syncthreads();
  {
    int bb = t >> 7, o = t & 127;
    float s = 0.f;
    #pragma unroll
    for (int j = 0; j < 8; ++j) s += h1[bb][j] * w2[o*8 + j];
    lgt[bb][o] = s;
  }
  __syncthreads();
  if (t < 2) {
    float mx = -3.4e38f;
    for (int o = 0; o < 128; ++o) mx = fmaxf(mx, lgt[t][o]);
    float d = 0.f;
    for (int o = 0; o < 128; ++o) d += __expf(lgt[t][o] - mx);
    mred[t] = mx; dred[t] = d;
  }
  __syncthreads();
  {
    int bb = t >> 7, o = t & 127;
    sea[bb*128 + o] = __expf(lgt[bb][o] - mred[bb]) / dred[bb];
  }
}

// ---------------- epilogue: h-channels (transpose back) ----------------
__global__ void k_ep_h(const ushort_t* __restrict__ Oh1, const ushort_t* __restrict__ Oh2,
                       const float* __restrict__ xl, const float* __restrict__ xr,
                       const float* __restrict__ ls1, const float* __restrict__ ls2,
                       float* __restrict__ out) {
  __shared__ ushort_t Ls[64*72];
  int dir = blockIdx.y;
  const ushort_t* O = dir ? Oh2 : Oh1;
  const float* xin = dir ? xr : xl;
  float lsv = (dir ? ls2 : ls1)[blockIdx.x % 576 / 9];
  int bx = blockIdx.x;                    // 1152 = 2b * 64c * 9 tiles
  int b = bx / 576, rem = bx % 576;
  int c = rem / 9, tt = rem % 9;
  int h0 = (tt/3)*64, w0 = (tt%3)*64;
  int tid = threadIdx.x;
  const ushort_t* Ob = O + (size_t)(b*64 + c)*NN;
  const float* xb = xin + (size_t)(b*192 + c)*NN;
  float* ob = out + (size_t)dir*TOT + (size_t)(b*192 + c)*NN;
  #pragma unroll
  for (int i = 0; i < 2; ++i) {
    int idx = tid + 256*i;
    int ww = idx >> 3, hb = idx & 7;
    *(u32x4*)&Ls[ww*72 + hb*8] = *(const u32x4*)&Ob[(w0+ww)*192 + h0 + hb*8];
  }
  __syncthreads();
  #pragma unroll
  for (int i = 0; i < 2; ++i) {
    int idx = tid + 256*i;
    int hh = idx >> 3, wb = idx & 7;
    int base = (h0+hh)*192 + w0 + wb*8;
    f32x4 xa = *(const f32x4*)&xb[base];
    f32x4 xc = *(const f32x4*)&xb[base + 4];
    f32x4 r0, r1;
    #pragma unroll
    for (int j = 0; j < 4; ++j) r0[j] = bf2f(Ls[(wb*8+j)*72 + hh])*lsv + xa[j];
    #pragma unroll
    for (int j = 0; j < 4; ++j) r1[j] = bf2f(Ls[(wb*8+4+j)*72 + hh])*lsv + xc[j];
    *(f32x4*)&ob[base] = r0;
    *(f32x4*)&ob[base + 4] = r1;
  }
}

// ---------------- epilogue: w-channels + SE channels (elementwise) ----------------
__global__ void k_ep_wc(const ushort_t* __restrict__ Ow1, const ushort_t* __restrict__ Ow2,
                        const ushort_t* __restrict__ Vl, const ushort_t* __restrict__ Vr,
                        const float* __restrict__ sea,
                        const float* __restrict__ xl, const float* __restrict__ xr,
                        const float* __restrict__ ls1, const float* __restrict__ ls2,
                        float* __restrict__ out) {
  int gid = blockIdx.x;                   // 9216 = 2dir * 2b * 128c * 18 tiles
  int tile = gid % 18;
  int c128 = (gid / 18) % 128;
  int b = (gid / (18*128)) % 2;
  int dir = gid / (18*128*2);
  int cg = 64 + c128;
  const float* xin = dir ? xr : xl;
  float lsv = (dir ? ls2 : ls1)[cg];
  int n0 = tile*2048 + threadIdx.x*8;
  size_t xo = (size_t)(b*192 + cg)*NN + n0;
  const ushort_t* src;
  float mult;
  if (c128 < 64) {
    src = (dir ? Ow2 : Ow1) + (size_t)(b*64 + c128)*NN + n0;
    mult = lsv;
  } else {
    int cc = c128 - 64;
    src = (dir ? Vr : Vl) + (size_t)(b*192 + 128 + cc)*NN + n0;
    mult = lsv * sea[b*128 + dir*64 + cc];
  }
  u32x4 sv = *(const u32x4*)src;
  const ushort_t* sp = (const ushort_t*)&sv;
  f32x4 xa = *(const f32x4*)&xin[xo];
  f32x4 xb = *(const f32x4*)&xin[xo + 4];
  f32x4 r0, r1;
  #pragma unroll
  for (int j = 0; j < 4; ++j) r0[j] = bf2f(sp[j])*mult + xa[j];
  #pragma unroll
  for (int j = 0; j < 4; ++j) r1[j] = bf2f(sp[4+j])*mult + xb[j];
  float* ob = out + (size_t)dir*TOT;
  *(f32x4*)&ob[xo] = r0;
  *(f32x4*)&ob[xo + 4] = r1;
}

extern "C" void kernel_launch(void* const* d_in, const int* in_sizes, int n_in,
                              void* d_out, int out_size, void* d_ws, size_t ws_size,
                              hipStream_t stream) {
  const float* x_l  = (const float*)d_in[0];
  const float* x_r  = (const float*)d_in[1];
  const float* lnlw = (const float*)d_in[2];
  const float* lnlb = (const float*)d_in[3];
  const float* lnrw = (const float*)d_in[4];
  const float* lnrb = (const float*)d_in[5];
  const float* wq_l = (const float*)d_in[6];
  const float* wq_r = (const float*)d_in[7];
  const float* wv_l = (const float*)d_in[8];
  const float* wv_r = (const float*)d_in[9];
  const float* w1   = (const float*)d_in[10];
  const float* w2   = (const float*)d_in[11];
  const float* sch  = (const float*)d_in[12];
  const float* scw  = (const float*)d_in[13];
  const float* ls1  = (const float*)d_in[14];
  const float* ls2  = (const float*)d_in[15];
  float* out = (float*)d_out;

  char* ws = (char*)d_ws;
  size_t off = 0;
  auto alloc = [&](size_t bytes) {
    char* p = ws + off;
    off += (bytes + 255) & ~(size_t)255;
    return p;
  };
  ushort_t* Ql   = (ushort_t*)alloc((size_t)2*128*NN*2);
  ushort_t* Qr   = (ushort_t*)alloc((size_t)2*128*NN*2);
  ushort_t* Vl   = (ushort_t*)alloc((size_t)2*192*NN*2);
  ushort_t* Vr   = (ushort_t*)alloc((size_t)2*192*NN*2);
  ushort_t* qhTl = (ushort_t*)alloc((size_t)2*64*NN*2);
  ushort_t* qhTr = (ushort_t*)alloc((size_t)2*64*NN*2);
  ushort_t* qwTl = (ushort_t*)alloc((size_t)2*64*NN*2);
  ushort_t* qwTr = (ushort_t*)alloc((size_t)2*64*NN*2);
  ushort_t* vhTl = (ushort_t*)alloc((size_t)2*64*NN*2);
  ushort_t* vhTr = (ushort_t*)alloc((size_t)2*64*NN*2);
  ushort_t* Oh1  = (ushort_t*)alloc((size_t)2*64*NN*2);
  ushort_t* Oh2  = (ushort_t*)alloc((size_t)2*64*NN*2);
  ushort_t* Ow1  = (ushort_t*)alloc((size_t)2*64*NN*2);
  ushort_t* Ow2  = (ushort_t*)alloc((size_t)2*64*NN*2);
  ushort_t* Wl   = (ushort_t*)alloc((size_t)384*192*2);
  ushort_t* Wr   = (ushort_t*)alloc((size_t)384*192*2);
  float* abl = (float*)alloc(384*4);
  float* abr = (float*)alloc(384*4);
  float* stl = (float*)alloc((size_t)4*NN*4);
  float* str = (float*)alloc((size_t)4*NN*4);
  float* gap = (float*)alloc(2*64*4);
  float* sea = (float*)alloc(2*128*4);
  (void)in_sizes; (void)n_in; (void)out_size; (void)ws_size;

  hipMemsetAsync(gap, 0, 2*64*4, stream);
  k_prep<<<384, 192, 0, stream>>>(wq_l, wv_l, lnlw, lnlb, Wl, abl);
  k_prep<<<384, 192, 0, stream>>>(wq_r, wv_r, lnrw, lnrb, Wr, abr);
  k_stats<<<576, 256, 0, stream>>>(x_l, x_r, stl, str);
  k_proj<<<dim3(1152, 2), 256, 0, stream>>>(x_l, x_r, Wl, Wr, abl, abr, stl, str,
                                            Ql, Qr, Vl, Vr, gap);
  k_repack_q<<<dim3(1152, 4), 256, 0, stream>>>(Ql, Qr, qhTl, qhTr, qwTl, qwTr);
  k_repack_v<<<dim3(1152, 2), 256, 0, stream>>>(Vl, Vr, vhTl, vhTr);
  k_attn<0><<<384, 256, 0, stream>>>(qhTl, qhTr, vhTl, vhTr, sch, Oh1, Oh2);
  k_attn<1><<<384, 256, 0, stream>>>(qwTl, qwTr, Vl, Vr, scw, Ow1, Ow2);
  k_se<<<1, 256, 0, stream>>>(gap, w1, w2, sea);
  k_ep_h<<<dim3(1152, 2), 256, 0, stream>>>(Oh1, Oh2, x_l, x_r, ls1, ls2, out);
  k_ep_wc<<<9216, 256, 0, stream>>>(Ow1, Ow2, Vl, Vr, sea, x_l, x_r, ls1, ls2, out);
}

// Round 2
// 331.068 us; speedup vs baseline: 1.4290x; 1.4290x over previous
//
#include <hip/hip_runtime.h>
#include <stdint.h>

#define NN 36864        // 192*192 spatial
#define PL 7077888      // 192*NN  per-batch full-C plane
#define PL64 2359296    // 64*NN
#define TOT 14155776    // 2*192*NN elements per output tensor

typedef unsigned short ushort_t;
typedef __attribute__((ext_vector_type(8))) __bf16 bf16x8;
typedef __attribute__((ext_vector_type(4))) float f32x4;
typedef __attribute__((ext_vector_type(4))) unsigned int u32x4;

__device__ __forceinline__ ushort_t f2bf(float f) {
  unsigned int u = __builtin_bit_cast(unsigned int, f);
  u = (u + 0x7FFFu + ((u >> 16) & 1u)) >> 16;   // RNE
  return (ushort_t)u;
}
__device__ __forceinline__ float bf2f(ushort_t h) {
  unsigned int u = ((unsigned int)h) << 16;
  return __builtin_bit_cast(float, u);
}
__device__ __forceinline__ bf16x8 lds8(const ushort_t* p) {
  return __builtin_bit_cast(bf16x8, *(const u32x4*)p);
}
__device__ __forceinline__ f32x4 mfma16(bf16x8 a, bf16x8 b, f32x4 c) {
  return __builtin_amdgcn_mfma_f32_16x16x32_bf16(a, b, c, 0, 0, 0);
}

// ---------------- weight prep: Wstack = [wq*lnw ; wv] bf16, alpha/beta ----------------
__global__ void k_prep(const float* __restrict__ wq, const float* __restrict__ wv,
                       const float* __restrict__ lnw, const float* __restrict__ lnb,
                       ushort_t* __restrict__ W, float* __restrict__ ab) {
  __shared__ float sa[3], sb[3];
  int r = blockIdx.x, t = threadIdx.x;   // 384 blocks x 192 threads
  if (r < 192) {
    float w  = wq[r*192 + t];
    float lw = lnw[t], lb = lnb[t];
    W[r*192 + t] = f2bf(w * lw);
    float av = w * lb, bv = -w * lw;
    #pragma unroll
    for (int off = 1; off < 64; off <<= 1) {
      av += __shfl_xor(av, off);
      bv += __shfl_xor(bv, off);
    }
    if ((t & 63) == 0) { sa[t >> 6] = av; sb[t >> 6] = bv; }
    __syncthreads();
    if (t == 0) { ab[r] = sa[0]+sa[1]+sa[2]; ab[192 + r] = sb[0]+sb[1]+sb[2]; }
  } else {
    W[r*192 + t] = f2bf(wv[(r-192)*192 + t]);
  }
}

// ---------------- LN stats over channel dim ----------------
__global__ void k_stats(const float* __restrict__ xl, const float* __restrict__ xr,
                        float* __restrict__ stl, float* __restrict__ str) {
  int bid = blockIdx.x;                  // 576 = 2 sides * 2 b * 144
  int side = bid / 288, rem = bid % 288;
  int b = rem / 144, nb = rem % 144;
  const float* x = side ? xr : xl;
  float* st = side ? str : stl;
  int n = nb*256 + threadIdx.x;
  const float* p = x + (size_t)b*PL + n;
  float s = 0.f, s2 = 0.f;
  #pragma unroll 4
  for (int c = 0; c < 192; ++c) { float v = p[(size_t)c*NN]; s += v; s2 += v*v; }
  float mu = s * (1.f/192.f);
  float var = s2 * (1.f/192.f) - mu*mu;
  st[(b*2+0)*NN + n] = mu;
  st[(b*2+1)*NN + n] = rsqrtf(var + 1e-6f);
}

// ---------------- projection GEMM v2: 128m x 192n tile, 8 waves, dbuf pipeline ----------------
// grid: x = (b*192+h)*3 + mb  (1152), y = side (2). block = 512 threads.
__global__ __launch_bounds__(512, 4) void k_proj(
    const float* __restrict__ xl, const float* __restrict__ xr,
    const ushort_t* __restrict__ Wl, const ushort_t* __restrict__ Wr,
    const float* __restrict__ abl, const float* __restrict__ abr,
    const float* __restrict__ stl, const float* __restrict__ str,
    ushort_t* __restrict__ qhTl, ushort_t* __restrict__ qhTr,
    ushort_t* __restrict__ qwTl, ushort_t* __restrict__ qwTr,
    ushort_t* __restrict__ Vl, ushort_t* __restrict__ Vr,
    float* __restrict__ gpart) {
  __shared__ union {
    struct { ushort_t A[2][4096]; ushort_t B[2][6144]; } kl;   // 40 KiB
    struct { ushort_t T[192*72]; float gsum[64]; } ep;         // 27.9 KiB
  } sm;

  const int side = blockIdx.y;
  const float*    x  = side ? xr  : xl;
  const ushort_t* W  = side ? Wr  : Wl;
  const float*    ab = side ? abr : abl;
  const float*    st = side ? str : stl;
  ushort_t* qhT = side ? qhTr : qhTl;
  ushort_t* qwT = side ? qwTr : qwTl;
  ushort_t* V   = side ? Vr   : Vl;

  const int bx = blockIdx.x;
  const int mb = bx % 3;
  const int bh = bx / 3;                 // b*192 + h
  const int b  = bh / 192, h = bh % 192;
  const int m0 = mb * 128;
  const int tid = threadIdx.x;
  const int wave = tid >> 6, lane = tid & 63, lr = lane & 15, lg = lane >> 4;
  const int wm = wave >> 2, wn = wave & 3;

  // B staging mapping (768 tasks: 512 pass0 + 256 pass1). task -> (kg 0..3, n 0..191)
  const int kg0 = tid / 192, n_0 = tid - kg0 * 192;
  const int id1 = 512 + (tid & 255);
  const int kg1 = id1 / 192, n_1 = id1 - kg1 * 192;
  const float* xb0 = x + (size_t)b*PL + (size_t)(kg0*8)*NN + h*192 + n_0;
  const float* xb1 = x + (size_t)b*PL + (size_t)(kg1*8)*NN + h*192 + n_1;
  const int bw0 = n_0*32 + 8*(kg0 ^ ((n_0 >> 1) & 3));
  const int bw1 = n_1*32 + 8*(kg1 ^ ((n_1 >> 1) & 3));
  // A staging: one 16B chunk per thread per step
  const int am = tid >> 2, akb = tid & 3;
  const ushort_t* wsrc = W + (m0 + am)*192 + akb*8;
  const int aw = am*32 + 8*(akb ^ ((am >> 1) & 3));
  // fragment read slot (uniform across mf/nf since row-bases are multiples of 8 after >>1)
  const int slotR = 8 * (lg ^ ((lr >> 1) & 3));

  const f32x4 fz = {0.f, 0.f, 0.f, 0.f};
  f32x4 acc[4][3];
  #pragma unroll
  for (int mf = 0; mf < 4; ++mf)
    #pragma unroll
    for (int nf = 0; nf < 3; ++nf) acc[mf][nf] = fz;

  // ---- prologue: stage step 0 into buffer 0 ----
  {
    u32x4 aV = *(const u32x4*)wsrc;
    float g0[8], g1[8];
    #pragma unroll
    for (int j = 0; j < 8; ++j) g0[j] = xb0[(size_t)j*NN];
    if (tid < 256) {
      #pragma unroll
      for (int j = 0; j < 8; ++j) g1[j] = xb1[(size_t)j*NN];
    }
    *(u32x4*)&sm.kl.A[0][aw] = aV;
    union { ushort_t us[8]; u32x4 v; } t0;
    #pragma unroll
    for (int j = 0; j < 8; ++j) t0.us[j] = f2bf(g0[j]);
    *(u32x4*)&sm.kl.B[0][bw0] = t0.v;
    if (tid < 256) {
      union { ushort_t us[8]; u32x4 v; } t1;
      #pragma unroll
      for (int j = 0; j < 8; ++j) t1.us[j] = f2bf(g1[j]);
      *(u32x4*)&sm.kl.B[0][bw1] = t1.v;
    }
  }
  __syncthreads();

  // ---- main loop: issue next-step loads early, ds_write after compute (T14) ----
  for (int ks = 0; ks < 6; ++ks) {
    const int cur = ks & 1, nxt = cur ^ 1;
    u32x4 aN;
    float g0[8], g1[8];
    if (ks < 5) {
      const int k0n = (ks + 1) * 32;
      aN = *(const u32x4*)(wsrc + k0n);
      #pragma unroll
      for (int j = 0; j < 8; ++j) g0[j] = xb0[(size_t)(k0n + j)*NN];
      if (tid < 256) {
        #pragma unroll
        for (int j = 0; j < 8; ++j) g1[j] = xb1[(size_t)(k0n + j)*NN];
      }
    }
    // compute current buffer
    bf16x8 bfr[3];
    #pragma unroll
    for (int nf = 0; nf < 3; ++nf)
      bfr[nf] = lds8(&sm.kl.B[cur][(wn*48 + nf*16 + lr)*32 + slotR]);
    #pragma unroll
    for (int mf = 0; mf < 4; ++mf) {
      bf16x8 af = lds8(&sm.kl.A[cur][(wm*64 + mf*16 + lr)*32 + slotR]);
      #pragma unroll
      for (int nf = 0; nf < 3; ++nf) acc[mf][nf] = mfma16(af, bfr[nf], acc[mf][nf]);
    }
    // write next buffer
    if (ks < 5) {
      *(u32x4*)&sm.kl.A[nxt][aw] = aN;
      union { ushort_t us[8]; u32x4 v; } t0;
      #pragma unroll
      for (int j = 0; j < 8; ++j) t0.us[j] = f2bf(g0[j]);
      *(u32x4*)&sm.kl.B[nxt][bw0] = t0.v;
      if (tid < 256) {
        union { ushort_t us[8]; u32x4 v; } t1;
        #pragma unroll
        for (int j = 0; j < 8; ++j) t1.us[j] = f2bf(g1[j]);
        *(u32x4*)&sm.kl.B[nxt][bw1] = t1.v;
      }
    }
    __syncthreads();
  }

  // ---- epilogue ----
  if (mb == 0) {
    // LN fixup for q rows 0..127
    float rst[3], mrs[3];
    #pragma unroll
    for (int nf = 0; nf < 3; ++nf) {
      int n_ = h*192 + wn*48 + nf*16 + lr;
      float rs = st[(b*2+1)*NN + n_];
      rst[nf] = rs;
      mrs[nf] = st[(b*2+0)*NN + n_] * rs;
    }
    #pragma unroll
    for (int mf = 0; mf < 4; ++mf) {
      #pragma unroll
      for (int i = 0; i < 4; ++i) {
        int m = wm*64 + mf*16 + lg*4 + i;
        float a_ = ab[m], bb = ab[192 + m];
        #pragma unroll
        for (int nf = 0; nf < 3; ++nf)
          acc[mf][nf][i] = acc[mf][nf][i]*rst[nf] + bb*mrs[nf] + a_;
      }
    }
    // pass A: q_h channels (c 0..63) via LDS transpose -> qhT [b][w][h][c]
    if (wm == 0) {
      #pragma unroll
      for (int mf = 0; mf < 4; ++mf)
        #pragma unroll
        for (int nf = 0; nf < 3; ++nf)
          #pragma unroll
          for (int i = 0; i < 4; ++i)
            sm.ep.T[(wn*48 + nf*16 + lr)*72 + mf*16 + lg*4 + i] = f2bf(acc[mf][nf][i]);
    }
    __syncthreads();
    #pragma unroll
    for (int p = 0; p < 3; ++p) {
      int id = p*512 + tid, n = id >> 3, c8 = id & 7;
      u32x4 v = *(const u32x4*)&sm.ep.T[n*72 + c8*8];
      *(u32x4*)&qhT[(((size_t)b*192 + n)*192 + h)*64 + c8*8] = v;
    }
    __syncthreads();
    // pass B: q_w channels (c 64..127) -> qwT [b][h][w][c] (contiguous)
    if (wm == 1) {
      #pragma unroll
      for (int mf = 0; mf < 4; ++mf)
        #pragma unroll
        for (int nf = 0; nf < 3; ++nf)
          #pragma unroll
          for (int i = 0; i < 4; ++i)
            sm.ep.T[(wn*48 + nf*16 + lr)*72 + mf*16 + lg*4 + i] = f2bf(acc[mf][nf][i]);
    }
    __syncthreads();
    #pragma unroll
    for (int p = 0; p < 3; ++p) {
      int id = p*512 + tid, n = id >> 3, c8 = id & 7;
      u32x4 v = *(const u32x4*)&sm.ep.T[n*72 + c8*8];
      *(u32x4*)&qwT[(((size_t)b*192 + h)*192 + n)*64 + c8*8] = v;
    }
  } else {
    if (mb == 1 && tid < 64) sm.ep.gsum[tid] = 0.f;
    __syncthreads();
    if (mb == 1) {
      if (wm == 0) {
        // q_c rows 128..191: LN fixup + row-sum -> LDS gsum (no global atomics)
        float rst[3], mrs[3];
        #pragma unroll
        for (int nf = 0; nf < 3; ++nf) {
          int n_ = h*192 + wn*48 + nf*16 + lr;
          float rs = st[(b*2+1)*NN + n_];
          rst[nf] = rs;
          mrs[nf] = st[(b*2+0)*NN + n_] * rs;
        }
        #pragma unroll
        for (int mf = 0; mf < 4; ++mf) {
          #pragma unroll
          for (int i = 0; i < 4; ++i) {
            int m = 128 + mf*16 + lg*4 + i;
            float a_ = ab[m], bb = ab[192 + m];
            float part = 0.f;
            #pragma unroll
            for (int nf = 0; nf < 3; ++nf)
              part += acc[mf][nf][i]*rst[nf] + bb*mrs[nf] + a_;
            #pragma unroll
            for (int off = 1; off < 16; off <<= 1) part += __shfl_xor(part, off);
            if (lr == 0) atomicAdd(&sm.ep.gsum[mf*16 + lg*4 + i], part);
          }
        }
      } else {
        // V rows 192..255 -> V channels 0..63
        #pragma unroll
        for (int mf = 0; mf < 4; ++mf)
          #pragma unroll
          for (int i = 0; i < 4; ++i) {
            int c = mf*16 + lg*4 + i;
            #pragma unroll
            for (int nf = 0; nf < 3; ++nf)
              V[((size_t)b*192 + c)*NN + h*192 + wn*48 + nf*16 + lr] = f2bf(acc[mf][nf][i]);
          }
      }
      __syncthreads();
      if (tid < 64) gpart[(((size_t)side*2 + b)*192 + h)*64 + tid] = sm.ep.gsum[tid];
    } else {
      // mb == 2: V rows 256..383 -> V channels 64..191
      #pragma unroll
      for (int mf = 0; mf < 4; ++mf)
        #pragma unroll
        for (int i = 0; i < 4; ++i) {
          int c = 64 + wm*64 + mf*16 + lg*4 + i;
          #pragma unroll
          for (int nf = 0; nf < 3; ++nf)
            V[((size_t)b*192 + c)*NN + h*192 + wn*48 + nf*16 + lr] = f2bf(acc[mf][nf][i]);
        }
    }
  }
}

// ---------------- repack v_h (ch 0..63 of V): [b][c][h][w] -> [b][c][w][h] ----------------
__global__ void k_repack_v(const ushort_t* __restrict__ Vl, const ushort_t* __restrict__ Vr,
                           ushort_t* __restrict__ vhTl, ushort_t* __restrict__ vhTr) {
  __shared__ ushort_t Ls[64*72];
  const ushort_t* V = blockIdx.y ? Vr : Vl;
  ushort_t* out = blockIdx.y ? vhTr : vhTl;
  int bx = blockIdx.x;                    // 1152 = 2b * 64c * 9 tiles
  int b = bx / 576, rem = bx % 576;
  int c = rem / 9, tt = rem % 9;
  int h0 = (tt/3)*64, w0 = (tt%3)*64;
  int tid = threadIdx.x;
  #pragma unroll
  for (int i = 0; i < 2; ++i) {
    int idx = tid + 256*i;
    int hh = idx >> 3, wb = idx & 7;
    *(u32x4*)&Ls[hh*72 + wb*8] =
      *(const u32x4*)&V[(size_t)(b*192 + c)*NN + (h0+hh)*192 + w0 + wb*8];
  }
  __syncthreads();
  #pragma unroll
  for (int i = 0; i < 2; ++i) {
    int idx = tid + 256*i;
    int ww = idx >> 3, hb = idx & 7;
    union { ushort_t us[8]; u32x4 v; } tu;
    #pragma unroll
    for (int j = 0; j < 8; ++j) tu.us[j] = Ls[(hb*8+j)*72 + ww];
    *(u32x4*)&out[(size_t)(b*64 + c)*NN + (w0+ww)*192 + h0 + hb*8] = tu.v;
  }
}

// ---------------- axial attention, MODE 0 = height (T layouts), 1 = width ----------------
template<int MODE>
__global__ __launch_bounds__(256, 1) void k_attn(
    const ushort_t* __restrict__ qTl, const ushort_t* __restrict__ qTr,
    const ushort_t* __restrict__ Vlp, const ushort_t* __restrict__ Vrp,
    const float* __restrict__ scale_p,
    ushort_t* __restrict__ O1p, ushort_t* __restrict__ O2p) {
  __shared__ ushort_t Qsl[192*72];   // [spatial][c] pad72
  __shared__ ushort_t Qsr[192*72];
  __shared__ ushort_t Pls[192*200];  // P[col][row]
  __shared__ ushort_t Vs[64*200];    // [c][spatial] pad200
  __shared__ float md[192*2];

  const int tid = threadIdx.x;
  const int wave = tid >> 6, lane = tid & 63, lr = lane & 15, lg = lane >> 4;
  const int b = blockIdx.x / 192, s0 = blockIdx.x % 192;
  const float scl = scale_p[0];
  const f32x4 fz = {0.f, 0.f, 0.f, 0.f};

  const ushort_t* ql = qTl + (size_t)(b*192 + s0)*12288;
  const ushort_t* qr = qTr + (size_t)(b*192 + s0)*12288;
  const ushort_t* vr = MODE ? Vrp + (size_t)(b*192 + 64)*NN + s0*192
                            : Vrp + (size_t)b*PL64 + s0*192;
  const ushort_t* vl = MODE ? Vlp + (size_t)(b*192 + 64)*NN + s0*192
                            : Vlp + (size_t)b*PL64 + s0*192;
  ushort_t* o1 = O1p + (size_t)b*PL64 + s0*192;
  ushort_t* o2 = O2p + (size_t)b*PL64 + s0*192;

  #pragma unroll
  for (int i = 0; i < 6; ++i) {           // stage Q tiles + V_r
    int idx = tid + 256*i;
    int h = idx >> 3, cb = idx & 7;
    *(u32x4*)&Qsl[h*72 + cb*8] = *(const u32x4*)&ql[h*64 + cb*8];
    *(u32x4*)&Qsr[h*72 + cb*8] = *(const u32x4*)&qr[h*64 + cb*8];
    int c = idx / 24, gb = idx % 24;
    *(u32x4*)&Vs[c*200 + gb*8] = *(const u32x4*)&vr[(size_t)c*NN + gb*8];
  }
  __syncthreads();

  f32x4 acc[12][3];
  #pragma unroll
  for (int mf = 0; mf < 12; ++mf) {
    #pragma unroll
    for (int nf = 0; nf < 3; ++nf) acc[mf][nf] = fz;
  }
  // pass1: S^T frags (rows = softmax axis, cols = this wave's 48 of the other axis)
  #pragma unroll
  for (int kh = 0; kh < 2; ++kh) {
    const int k0 = kh * 32;
    bf16x8 bq[3];
    #pragma unroll
    for (int nf = 0; nf < 3; ++nf) {
      int n_ = wave*48 + nf*16 + lr;
      bq[nf] = lds8(&Qsl[n_*72 + k0 + lg*8]);
    }
    #pragma unroll
    for (int mf = 0; mf < 12; ++mf) {
      bf16x8 aq = lds8(&Qsr[(mf*16 + lr)*72 + k0 + lg*8]);
      #pragma unroll
      for (int nf = 0; nf < 3; ++nf) acc[mf][nf] = mfma16(aq, bq[nf], acc[mf][nf]);
    }
  }
  // softmax over rows per column; store (max,den) for H pass2
  #pragma unroll
  for (int nf = 0; nf < 3; ++nf) {
    float mx = -3.4e38f;
    #pragma unroll
    for (int mf = 0; mf < 12; ++mf) {
      #pragma unroll
      for (int i = 0; i < 4; ++i) {
        float v = acc[mf][nf][i] * scl;
        acc[mf][nf][i] = v;
        mx = fmaxf(mx, v);
      }
    }
    mx = fmaxf(mx, __shfl_xor(mx, 16));
    mx = fmaxf(mx, __shfl_xor(mx, 32));
    float den = 0.f;
    #pragma unroll
    for (int mf = 0; mf < 12; ++mf) {
      #pragma unroll
      for (int i = 0; i < 4; ++i) {
        float e = __expf(acc[mf][nf][i] - mx);
        acc[mf][nf][i] = e;
        den += e;
      }
    }
    den += __shfl_xor(den, 16);
    den += __shfl_xor(den, 32);
    int col = wave*48 + nf*16 + lr;
    if (lg == 0) { md[col*2] = mx; md[col*2+1] = den; }
    float rd = 1.f / den;
    #pragma unroll
    for (int mf = 0; mf < 12; ++mf) {
      #pragma unroll
      for (int i = 0; i < 4; ++i)
        Pls[col*200 + mf*16 + lg*4 + i] = f2bf(acc[mf][nf][i] * rd);
    }
  }
  __syncthreads();

  {                                        // O1 = V_r x P1
    f32x4 o[4][3];
    #pragma unroll
    for (int mf = 0; mf < 4; ++mf) {
      #pragma unroll
      for (int nf = 0; nf < 3; ++nf) o[mf][nf] = fz;
    }
    #pragma unroll
    for (int ks = 0; ks < 6; ++ks) {
      int k0 = ks * 32;
      bf16x8 bp[3];
      #pragma unroll
      for (int nf = 0; nf < 3; ++nf) {
        int n_ = wave*48 + nf*16 + lr;
        bp[nf] = lds8(&Pls[n_*200 + k0 + lg*8]);
      }
      #pragma unroll
      for (int mf = 0; mf < 4; ++mf) {
        bf16x8 av = lds8(&Vs[(mf*16 + lr)*200 + k0 + lg*8]);
        #pragma unroll
        for (int nf = 0; nf < 3; ++nf) o[mf][nf] = mfma16(av, bp[nf], o[mf][nf]);
      }
    }
    #pragma unroll
    for (int mf = 0; mf < 4; ++mf) {
      #pragma unroll
      for (int i = 0; i < 4; ++i) {
        #pragma unroll
        for (int nf = 0; nf < 3; ++nf)
          o1[(size_t)(mf*16 + lg*4 + i)*NN + wave*48 + nf*16 + lr] = f2bf(o[mf][nf][i]);
      }
    }
  }
  __syncthreads();

  #pragma unroll
  for (int i = 0; i < 6; ++i) {            // stage V_l over Vs
    int idx = tid + 256*i;
    int c = idx / 24, gb = idx % 24;
    *(u32x4*)&Vs[c*200 + gb*8] = *(const u32x4*)&vl[(size_t)c*NN + gb*8];
  }

  // pass2: S frags with swapped roles
  #pragma unroll
  for (int mf = 0; mf < 12; ++mf) {
    #pragma unroll
    for (int nf = 0; nf < 3; ++nf) acc[mf][nf] = fz;
  }
  #pragma unroll
  for (int kh = 0; kh < 2; ++kh) {
    const int k0 = kh * 32;
    bf16x8 bq[3];
    #pragma unroll
    for (int nf = 0; nf < 3; ++nf) {
      int n_ = wave*48 + nf*16 + lr;
      bq[nf] = lds8(&Qsr[n_*72 + k0 + lg*8]);
    }
    #pragma unroll
    for (int mf = 0; mf < 12; ++mf) {
      bf16x8 aq = lds8(&Qsl[(mf*16 + lr)*72 + k0 + lg*8]);
      #pragma unroll
      for (int nf = 0; nf < 3; ++nf) acc[mf][nf] = mfma16(aq, bq[nf], acc[mf][nf]);
    }
  }
  if (MODE == 0) {                         // H: reuse softmax stats keyed by row h
    #pragma unroll
    for (int mf = 0; mf < 12; ++mf) {
      #pragma unroll
      for (int i = 0; i < 4; ++i) {
        int row = mf*16 + lg*4 + i;
        float mx = md[row*2];
        float rd = 1.f / md[row*2+1];
        #pragma unroll
        for (int nf = 0; nf < 3; ++nf) {
          int col = wave*48 + nf*16 + lr;
          Pls[col*200 + row] = f2bf(__expf(acc[mf][nf][i]*scl - mx) * rd);
        }
      }
    }
  } else {                                 // W: independent second softmax (over w, per v)
    #pragma unroll
    for (int nf = 0; nf < 3; ++nf) {
      float mx = -3.4e38f;
      #pragma unroll
      for (int mf = 0; mf < 12; ++mf) {
        #pragma unroll
        for (int i = 0; i < 4; ++i) {
          float v = acc[mf][nf][i] * scl;
          acc[mf][nf][i] = v;
          mx = fmaxf(mx, v);
        }
      }
      mx = fmaxf(mx, __shfl_xor(mx, 16));
      mx = fmaxf(mx, __shfl_xor(mx, 32));
      float den = 0.f;
      #pragma unroll
      for (int mf = 0; mf < 12; ++mf) {
        #pragma unroll
        for (int i = 0; i < 4; ++i) {
          float e = __expf(acc[mf][nf][i] - mx);
          acc[mf][nf][i] = e;
          den += e;
        }
      }
      den += __shfl_xor(den, 16);
      den += __shfl_xor(den, 32);
      int col = wave*48 + nf*16 + lr;
      float rd = 1.f / den;
      #pragma unroll
      for (int mf = 0; mf < 12; ++mf) {
        #pragma unroll
        for (int i = 0; i < 4; ++i)
          Pls[col*200 + mf*16 + lg*4 + i] = f2bf(acc[mf][nf][i] * rd);
      }
    }
  }
  __syncthreads();

  {                                        // O2 = V_l x P2
    f32x4 o[4][3];
    #pragma unroll
    for (int mf = 0; mf < 4; ++mf) {
      #pragma unroll
      for (int nf = 0; nf < 3; ++nf) o[mf][nf] = fz;
    }
    #pragma unroll
    for (int ks = 0; ks < 6; ++ks) {
      int k0 = ks * 32;
      bf16x8 bp[3];
      #pragma unroll
      for (int nf = 0; nf < 3; ++nf) {
        int n_ = wave*48 + nf*16 + lr;
        bp[nf] = lds8(&Pls[n_*200 + k0 + lg*8]);
      }
      #pragma unroll
      for (int mf = 0; mf < 4; ++mf) {
        bf16x8 av = lds8(&Vs[(mf*16 + lr)*200 + k0 + lg*8]);
        #pragma unroll
        for (int nf = 0; nf < 3; ++nf) o[mf][nf] = mfma16(av, bp[nf], o[mf][nf]);
      }
    }
    #pragma unroll
    for (int mf = 0; mf < 4; ++mf) {
      #pragma unroll
      for (int i = 0; i < 4; ++i) {
        #pragma unroll
        for (int nf = 0; nf < 3; ++nf)
          o2[(size_t)(mf*16 + lg*4 + i)*NN + wave*48 + nf*16 + lr] = f2bf(o[mf][nf][i]);
      }
    }
  }
}

// ---------------- SE: reduce gpart + MLP ----------------
__global__ void k_se(const float* __restrict__ gpart, const float* __restrict__ w1,
                     const float* __restrict__ w2, float* __restrict__ sea) {
  __shared__ float p[2][64];
  __shared__ float h1[2][8];
  __shared__ float lgt[2][128];
  __shared__ float mred[2], dred[2];
  int t = threadIdx.x;
  if (t < 128) {
    int b = t >> 6, c = t & 63;
    float s = 0.f;
    for (int side = 0; side < 2; ++side)
      for (int h = 0; h < 192; ++h)
        s += gpart[(((size_t)side*2 + b)*192 + h)*64 + c];
    p[b][c] = s * (1.f/36864.f);
  }
  __syncthreads();
  if (t < 16) {
    int bb = t >> 3, j = t & 7;
    float s = 0.f;
    for (int k = 0; k < 64; ++k) s += p[bb][k] * w1[j*64 + k];
    h1[bb][j] = fmaxf(s, 0.f);
  }
  __syncthreads();
  {
    int bb = t >> 7, o = t & 127;
    float s = 0.f;
    #pragma unroll
    for (int j = 0; j < 8; ++j) s += h1[bb][j] * w2[o*8 + j];
    lgt[bb][o] = s;
  }
  __syncthreads();
  if (t < 2) {
    float mx = -3.4e38f;
    for (int o = 0; o < 128; ++o) mx = fmaxf(mx, lgt[t][o]);
    float d = 0.f;
    for (int o = 0; o < 128; ++o) d += __expf(lgt[t][o] - mx);
    mred[t] = mx; dred[t] = d;
  }
  __syncthreads();
  {
    int bb = t >> 7, o = t & 127;
    sea[bb*128 + o] = __expf(lgt[bb][o] - mred[bb]) / dred[bb];
  }
}

// ---------------- epilogue: h-channels (transpose back) ----------------
__global__ void k_ep_h(const ushort_t* __restrict__ Oh1, const ushort_t* __restrict__ Oh2,
                       const float* __restrict__ xl, const float* __restrict__ xr,
                       const float* __restrict__ ls1, const float* __restrict__ ls2,
                       float* __restrict__ out) {
  __shared__ ushort_t Ls[64*72];
  int dir = blockIdx.y;
  const ushort_t* O = dir ? Oh2 : Oh1;
  const float* xin = dir ? xr : xl;
  float lsv = (dir ? ls2 : ls1)[blockIdx.x % 576 / 9];
  int bx = blockIdx.x;                    // 1152 = 2b * 64c * 9 tiles
  int b = bx / 576, rem = bx % 576;
  int c = rem / 9, tt = rem % 9;
  int h0 = (tt/3)*64, w0 = (tt%3)*64;
  int tid = threadIdx.x;
  const ushort_t* Ob = O + (size_t)(b*64 + c)*NN;
  const float* xb = xin + (size_t)(b*192 + c)*NN;
  float* ob = out + (size_t)dir*TOT + (size_t)(b*192 + c)*NN;
  #pragma unroll
  for (int i = 0; i < 2; ++i) {
    int idx = tid + 256*i;
    int ww = idx >> 3, hb = idx & 7;
    *(u32x4*)&Ls[ww*72 + hb*8] = *(const u32x4*)&Ob[(w0+ww)*192 + h0 + hb*8];
  }
  __syncthreads();
  #pragma unroll
  for (int i = 0; i < 2; ++i) {
    int idx = tid + 256*i;
    int hh = idx >> 3, wb = idx & 7;
    int base = (h0+hh)*192 + w0 + wb*8;
    f32x4 xa = *(const f32x4*)&xb[base];
    f32x4 xc = *(const f32x4*)&xb[base + 4];
    f32x4 r0, r1;
    #pragma unroll
    for (int j = 0; j < 4; ++j) r0[j] = bf2f(Ls[(wb*8+j)*72 + hh])*lsv + xa[j];
    #pragma unroll
    for (int j = 0; j < 4; ++j) r1[j] = bf2f(Ls[(wb*8+4+j)*72 + hh])*lsv + xc[j];
    *(f32x4*)&ob[base] = r0;
    *(f32x4*)&ob[base + 4] = r1;
  }
}

// ---------------- epilogue: w-channels + SE channels (elementwise) ----------------
__global__ void k_ep_wc(const ushort_t* __restrict__ Ow1, const ushort_t* __restrict__ Ow2,
                        const ushort_t* __restrict__ Vl, const ushort_t* __restrict__ Vr,
                        const float* __restrict__ sea,
                        const float* __restrict__ xl, const float* __restrict__ xr,
                        const float* __restrict__ ls1, const float* __restrict__ ls2,
                        float* __restrict__ out) {
  int gid = blockIdx.x;                   // 9216 = 2dir * 2b * 128c * 18 tiles
  int tile = gid % 18;
  int c128 = (gid / 18) % 128;
  int b = (gid / (18*128)) % 2;
  int dir = gid / (18*128*2);
  int cg = 64 + c128;
  const float* xin = dir ? xr : xl;
  float lsv = (dir ? ls2 : ls1)[cg];
  int n0 = tile*2048 + threadIdx.x*8;
  size_t xo = (size_t)(b*192 + cg)*NN + n0;
  const ushort_t* src;
  float mult;
  if (c128 < 64) {
    src = (dir ? Ow2 : Ow1) + (size_t)(b*64 + c128)*NN + n0;
    mult = lsv;
  } else {
    int cc = c128 - 64;
    src = (dir ? Vr : Vl) + (size_t)(b*192 + 128 + cc)*NN + n0;
    mult = lsv * sea[b*128 + dir*64 + cc];
  }
  u32x4 sv = *(const u32x4*)src;
  const ushort_t* sp = (const ushort_t*)&sv;
  f32x4 xa = *(const f32x4*)&xin[xo];
  f32x4 xb = *(const f32x4*)&xin[xo + 4];
  f32x4 r0, r1;
  #pragma unroll
  for (int j = 0; j < 4; ++j) r0[j] = bf2f(sp[j])*mult + xa[j];
  #pragma unroll
  for (int j = 0; j < 4; ++j) r1[j] = bf2f(sp[4+j])*mult + xb[j];
  float* ob = out + (size_t)dir*TOT;
  *(f32x4*)&ob[xo] = r0;
  *(f32x4*)&ob[xo + 4] = r1;
}

extern "C" void kernel_launch(void* const* d_in, const int* in_sizes, int n_in,
                              void* d_out, int out_size, void* d_ws, size_t ws_size,
                              hipStream_t stream) {
  const float* x_l  = (const float*)d_in[0];
  const float* x_r  = (const float*)d_in[1];
  const float* lnlw = (const float*)d_in[2];
  const float* lnlb = (const float*)d_in[3];
  const float* lnrw = (const float*)d_in[4];
  const float* lnrb = (const float*)d_in[5];
  const float* wq_l = (const float*)d_in[6];
  const float* wq_r = (const float*)d_in[7];
  const float* wv_l = (const float*)d_in[8];
  const float* wv_r = (const float*)d_in[9];
  const float* w1   = (const float*)d_in[10];
  const float* w2   = (const float*)d_in[11];
  const float* sch  = (const float*)d_in[12];
  const float* scw  = (const float*)d_in[13];
  const float* ls1  = (const float*)d_in[14];
  const float* ls2  = (const float*)d_in[15];
  float* out = (float*)d_out;

  char* ws = (char*)d_ws;
  size_t off = 0;
  auto alloc = [&](size_t bytes) {
    char* p = ws + off;
    off += (bytes + 255) & ~(size_t)255;
    return p;
  };
  ushort_t* Vl   = (ushort_t*)alloc((size_t)2*192*NN*2);
  ushort_t* Vr   = (ushort_t*)alloc((size_t)2*192*NN*2);
  ushort_t* qhTl = (ushort_t*)alloc((size_t)2*64*NN*2);
  ushort_t* qhTr = (ushort_t*)alloc((size_t)2*64*NN*2);
  ushort_t* qwTl = (ushort_t*)alloc((size_t)2*64*NN*2);
  ushort_t* qwTr = (ushort_t*)alloc((size_t)2*64*NN*2);
  ushort_t* vhTl = (ushort_t*)alloc((size_t)2*64*NN*2);
  ushort_t* vhTr = (ushort_t*)alloc((size_t)2*64*NN*2);
  ushort_t* Oh1  = (ushort_t*)alloc((size_t)2*64*NN*2);
  ushort_t* Oh2  = (ushort_t*)alloc((size_t)2*64*NN*2);
  ushort_t* Ow1  = (ushort_t*)alloc((size_t)2*64*NN*2);
  ushort_t* Ow2  = (ushort_t*)alloc((size_t)2*64*NN*2);
  ushort_t* Wl   = (ushort_t*)alloc((size_t)384*192*2);
  ushort_t* Wr   = (ushort_t*)alloc((size_t)384*192*2);
  float* abl = (float*)alloc(384*4);
  float* abr = (float*)alloc(384*4);
  float* stl = (float*)alloc((size_t)4*NN*4);
  float* str = (float*)alloc((size_t)4*NN*4);
  float* gpart = (float*)alloc((size_t)2*2*192*64*4);
  float* sea = (float*)alloc(2*128*4);
  (void)in_sizes; (void)n_in; (void)out_size; (void)ws_size;

  k_prep<<<384, 192, 0, stream>>>(wq_l, wv_l, lnlw, lnlb, Wl, abl);
  k_prep<<<384, 192, 0, stream>>>(wq_r, wv_r, lnrw, lnrb, Wr, abr);
  k_stats<<<576, 256, 0, stream>>>(x_l, x_r, stl, str);
  k_proj<<<dim3(1152, 2), 512, 0, stream>>>(x_l, x_r, Wl, Wr, abl, abr, stl, str,
                                            qhTl, qhTr, qwTl, qwTr, Vl, Vr, gpart);
  k_repack_v<<<dim3(1152, 2), 256, 0, stream>>>(Vl, Vr, vhTl, vhTr);
  k_attn<0><<<384, 256, 0, stream>>>(qhTl, qhTr, vhTl, vhTr, sch, Oh1, Oh2);
  k_attn<1><<<384, 256, 0, stream>>>(qwTl, qwTr, Vl, Vr, scw, Ow1, Ow2);
  k_se<<<1, 256, 0, stream>>>(gpart, w1, w2, sea);
  k_ep_h<<<dim3(1152, 2), 256, 0, stream>>>(Oh1, Oh2, x_l, x_r, ls1, ls2, out);
  k_ep_wc<<<9216, 256, 0, stream>>>(Ow1, Ow2, Vl, Vr, sea, x_l, x_r, ls1, ls2, out);
}

// Round 3
// 231.448 us; speedup vs baseline: 2.0441x; 1.4304x over previous
//
#include <hip/hip_runtime.h>
#include <stdint.h>

#define NN 36864        // 192*192 spatial
#define PL 7077888      // 192*NN  per-batch full-C plane
#define PL64 2359296    // 64*NN
#define TOT 14155776    // 2*192*NN elements per output tensor

typedef unsigned short ushort_t;
typedef __attribute__((ext_vector_type(8))) __bf16 bf16x8;
typedef __attribute__((ext_vector_type(4))) float f32x4;
typedef __attribute__((ext_vector_type(4))) unsigned int u32x4;

__device__ __forceinline__ ushort_t f2bf(float f) {
  unsigned int u = __builtin_bit_cast(unsigned int, f);
  u = (u + 0x7FFFu + ((u >> 16) & 1u)) >> 16;   // RNE
  return (ushort_t)u;
}
__device__ __forceinline__ float bf2f(ushort_t h) {
  unsigned int u = ((unsigned int)h) << 16;
  return __builtin_bit_cast(float, u);
}
__device__ __forceinline__ bf16x8 lds8(const ushort_t* p) {
  return __builtin_bit_cast(bf16x8, *(const u32x4*)p);
}
__device__ __forceinline__ f32x4 mfma16(bf16x8 a, bf16x8 b, f32x4 c) {
  return __builtin_amdgcn_mfma_f32_16x16x32_bf16(a, b, c, 0, 0, 0);
}
__device__ __forceinline__ unsigned cvtpk(float lo, float hi) {
  unsigned r;
  asm("v_cvt_pk_bf16_f32 %0, %1, %2" : "=v"(r) : "v"(lo), "v"(hi));
  return r;
}

// ---------------- weight prep: Wstack = [wq*lnw ; wv] bf16, alpha/beta ----------------
__global__ void k_prep(const float* __restrict__ wq, const float* __restrict__ wv,
                       const float* __restrict__ lnw, const float* __restrict__ lnb,
                       ushort_t* __restrict__ W, float* __restrict__ ab) {
  __shared__ float sa[3], sb[3];
  int r = blockIdx.x, t = threadIdx.x;   // 384 blocks x 192 threads
  if (r < 192) {
    float w  = wq[r*192 + t];
    float lw = lnw[t], lb = lnb[t];
    W[r*192 + t] = f2bf(w * lw);
    float av = w * lb, bv = -w * lw;
    #pragma unroll
    for (int off = 1; off < 64; off <<= 1) {
      av += __shfl_xor(av, off);
      bv += __shfl_xor(bv, off);
    }
    if ((t & 63) == 0) { sa[t >> 6] = av; sb[t >> 6] = bv; }
    __syncthreads();
    if (t == 0) { ab[r] = sa[0]+sa[1]+sa[2]; ab[192 + r] = sb[0]+sb[1]+sb[2]; }
  } else {
    W[r*192 + t] = f2bf(wv[(r-192)*192 + t]);
  }
}

// ---------------- LN stats over channel dim ----------------
__global__ void k_stats(const float* __restrict__ xl, const float* __restrict__ xr,
                        float* __restrict__ stl, float* __restrict__ str) {
  int bid = blockIdx.x;                  // 576 = 2 sides * 2 b * 144
  int side = bid / 288, rem = bid % 288;
  int b = rem / 144, nb = rem % 144;
  const float* x = side ? xr : xl;
  float* st = side ? str : stl;
  int n = nb*256 + threadIdx.x;
  const float* p = x + (size_t)b*PL + n;
  float s = 0.f, s2 = 0.f;
  #pragma unroll 4
  for (int c = 0; c < 192; ++c) { float v = p[(size_t)c*NN]; s += v; s2 += v*v; }
  float mu = s * (1.f/192.f);
  float var = s2 * (1.f/192.f) - mu*mu;
  st[(b*2+0)*NN + n] = mu;
  st[(b*2+1)*NN + n] = rsqrtf(var + 1e-6f);
}

// ---------------- projection GEMM: 128m x 192n tile, 8 waves, dbuf pipeline ----------------
__global__ __launch_bounds__(512, 4) void k_proj(
    const float* __restrict__ xl, const float* __restrict__ xr,
    const ushort_t* __restrict__ Wl, const ushort_t* __restrict__ Wr,
    const float* __restrict__ abl, const float* __restrict__ abr,
    const float* __restrict__ stl, const float* __restrict__ str,
    ushort_t* __restrict__ qhTl, ushort_t* __restrict__ qhTr,
    ushort_t* __restrict__ qwTl, ushort_t* __restrict__ qwTr,
    ushort_t* __restrict__ Vl, ushort_t* __restrict__ Vr,
    float* __restrict__ gpart) {
  __shared__ union {
    struct { ushort_t A[2][4096]; ushort_t B[2][6144]; } kl;   // 40 KiB
    struct { ushort_t T[192*72]; float gsum[64]; } ep;         // 27.9 KiB
  } sm;

  const int side = blockIdx.y;
  const float*    x  = side ? xr  : xl;
  const ushort_t* W  = side ? Wr  : Wl;
  const float*    ab = side ? abr : abl;
  const float*    st = side ? str : stl;
  ushort_t* qhT = side ? qhTr : qhTl;
  ushort_t* qwT = side ? qwTr : qwTl;
  ushort_t* V   = side ? Vr   : Vl;

  const int bx = blockIdx.x;
  const int mb = bx % 3;
  const int bh = bx / 3;                 // b*192 + h
  const int b  = bh / 192, h = bh % 192;
  const int m0 = mb * 128;
  const int tid = threadIdx.x;
  const int wave = tid >> 6, lane = tid & 63, lr = lane & 15, lg = lane >> 4;
  const int wm = wave >> 2, wn = wave & 3;

  const int kg0 = tid / 192, n_0 = tid - kg0 * 192;
  const int id1 = 512 + (tid & 255);
  const int kg1 = id1 / 192, n_1 = id1 - kg1 * 192;
  const float* xb0 = x + (size_t)b*PL + (size_t)(kg0*8)*NN + h*192 + n_0;
  const float* xb1 = x + (size_t)b*PL + (size_t)(kg1*8)*NN + h*192 + n_1;
  const int bw0 = n_0*32 + 8*(kg0 ^ ((n_0 >> 1) & 3));
  const int bw1 = n_1*32 + 8*(kg1 ^ ((n_1 >> 1) & 3));
  const int am = tid >> 2, akb = tid & 3;
  const ushort_t* wsrc = W + (m0 + am)*192 + akb*8;
  const int aw = am*32 + 8*(akb ^ ((am >> 1) & 3));
  const int slotR = 8 * (lg ^ ((lr >> 1) & 3));

  const f32x4 fz = {0.f, 0.f, 0.f, 0.f};
  f32x4 acc[4][3];
  #pragma unroll
  for (int mf = 0; mf < 4; ++mf)
    #pragma unroll
    for (int nf = 0; nf < 3; ++nf) acc[mf][nf] = fz;

  {
    u32x4 aV = *(const u32x4*)wsrc;
    float g0[8], g1[8];
    #pragma unroll
    for (int j = 0; j < 8; ++j) g0[j] = xb0[(size_t)j*NN];
    if (tid < 256) {
      #pragma unroll
      for (int j = 0; j < 8; ++j) g1[j] = xb1[(size_t)j*NN];
    }
    *(u32x4*)&sm.kl.A[0][aw] = aV;
    union { ushort_t us[8]; u32x4 v; } t0;
    #pragma unroll
    for (int j = 0; j < 8; ++j) t0.us[j] = f2bf(g0[j]);
    *(u32x4*)&sm.kl.B[0][bw0] = t0.v;
    if (tid < 256) {
      union { ushort_t us[8]; u32x4 v; } t1;
      #pragma unroll
      for (int j = 0; j < 8; ++j) t1.us[j] = f2bf(g1[j]);
      *(u32x4*)&sm.kl.B[0][bw1] = t1.v;
    }
  }
  __syncthreads();

  for (int ks = 0; ks < 6; ++ks) {
    const int cur = ks & 1, nxt = cur ^ 1;
    u32x4 aN;
    float g0[8], g1[8];
    if (ks < 5) {
      const int k0n = (ks + 1) * 32;
      aN = *(const u32x4*)(wsrc + k0n);
      #pragma unroll
      for (int j = 0; j < 8; ++j) g0[j] = xb0[(size_t)(k0n + j)*NN];
      if (tid < 256) {
        #pragma unroll
        for (int j = 0; j < 8; ++j) g1[j] = xb1[(size_t)(k0n + j)*NN];
      }
    }
    bf16x8 bfr[3];
    #pragma unroll
    for (int nf = 0; nf < 3; ++nf)
      bfr[nf] = lds8(&sm.kl.B[cur][(wn*48 + nf*16 + lr)*32 + slotR]);
    #pragma unroll
    for (int mf = 0; mf < 4; ++mf) {
      bf16x8 af = lds8(&sm.kl.A[cur][(wm*64 + mf*16 + lr)*32 + slotR]);
      #pragma unroll
      for (int nf = 0; nf < 3; ++nf) acc[mf][nf] = mfma16(af, bfr[nf], acc[mf][nf]);
    }
    if (ks < 5) {
      *(u32x4*)&sm.kl.A[nxt][aw] = aN;
      union { ushort_t us[8]; u32x4 v; } t0;
      #pragma unroll
      for (int j = 0; j < 8; ++j) t0.us[j] = f2bf(g0[j]);
      *(u32x4*)&sm.kl.B[nxt][bw0] = t0.v;
      if (tid < 256) {
        union { ushort_t us[8]; u32x4 v; } t1;
        #pragma unroll
        for (int j = 0; j < 8; ++j) t1.us[j] = f2bf(g1[j]);
        *(u32x4*)&sm.kl.B[nxt][bw1] = t1.v;
      }
    }
    __syncthreads();
  }

  if (mb == 0) {
    float rst[3], mrs[3];
    #pragma unroll
    for (int nf = 0; nf < 3; ++nf) {
      int n_ = h*192 + wn*48 + nf*16 + lr;
      float rs = st[(b*2+1)*NN + n_];
      rst[nf] = rs;
      mrs[nf] = st[(b*2+0)*NN + n_] * rs;
    }
    #pragma unroll
    for (int mf = 0; mf < 4; ++mf) {
      #pragma unroll
      for (int i = 0; i < 4; ++i) {
        int m = wm*64 + mf*16 + lg*4 + i;
        float a_ = ab[m], bb = ab[192 + m];
        #pragma unroll
        for (int nf = 0; nf < 3; ++nf)
          acc[mf][nf][i] = acc[mf][nf][i]*rst[nf] + bb*mrs[nf] + a_;
      }
    }
    if (wm == 0) {
      #pragma unroll
      for (int mf = 0; mf < 4; ++mf)
        #pragma unroll
        for (int nf = 0; nf < 3; ++nf)
          #pragma unroll
          for (int i = 0; i < 4; ++i)
            sm.ep.T[(wn*48 + nf*16 + lr)*72 + mf*16 + lg*4 + i] = f2bf(acc[mf][nf][i]);
    }
    __syncthreads();
    #pragma unroll
    for (int p = 0; p < 3; ++p) {
      int id = p*512 + tid, n = id >> 3, c8 = id & 7;
      u32x4 v = *(const u32x4*)&sm.ep.T[n*72 + c8*8];
      *(u32x4*)&qhT[(((size_t)b*192 + n)*192 + h)*64 + c8*8] = v;
    }
    __syncthreads();
    if (wm == 1) {
      #pragma unroll
      for (int mf = 0; mf < 4; ++mf)
        #pragma unroll
        for (int nf = 0; nf < 3; ++nf)
          #pragma unroll
          for (int i = 0; i < 4; ++i)
            sm.ep.T[(wn*48 + nf*16 + lr)*72 + mf*16 + lg*4 + i] = f2bf(acc[mf][nf][i]);
    }
    __syncthreads();
    #pragma unroll
    for (int p = 0; p < 3; ++p) {
      int id = p*512 + tid, n = id >> 3, c8 = id & 7;
      u32x4 v = *(const u32x4*)&sm.ep.T[n*72 + c8*8];
      *(u32x4*)&qwT[(((size_t)b*192 + h)*192 + n)*64 + c8*8] = v;
    }
  } else {
    if (mb == 1 && tid < 64) sm.ep.gsum[tid] = 0.f;
    __syncthreads();
    if (mb == 1) {
      if (wm == 0) {
        float rst[3], mrs[3];
        #pragma unroll
        for (int nf = 0; nf < 3; ++nf) {
          int n_ = h*192 + wn*48 + nf*16 + lr;
          float rs = st[(b*2+1)*NN + n_];
          rst[nf] = rs;
          mrs[nf] = st[(b*2+0)*NN + n_] * rs;
        }
        #pragma unroll
        for (int mf = 0; mf < 4; ++mf) {
          #pragma unroll
          for (int i = 0; i < 4; ++i) {
            int m = 128 + mf*16 + lg*4 + i;
            float a_ = ab[m], bb = ab[192 + m];
            float part = 0.f;
            #pragma unroll
            for (int nf = 0; nf < 3; ++nf)
              part += acc[mf][nf][i]*rst[nf] + bb*mrs[nf] + a_;
            #pragma unroll
            for (int off = 1; off < 16; off <<= 1) part += __shfl_xor(part, off);
            if (lr == 0) atomicAdd(&sm.ep.gsum[mf*16 + lg*4 + i], part);
          }
        }
      } else {
        #pragma unroll
        for (int mf = 0; mf < 4; ++mf)
          #pragma unroll
          for (int i = 0; i < 4; ++i) {
            int c = mf*16 + lg*4 + i;
            #pragma unroll
            for (int nf = 0; nf < 3; ++nf)
              V[((size_t)b*192 + c)*NN + h*192 + wn*48 + nf*16 + lr] = f2bf(acc[mf][nf][i]);
          }
      }
      __syncthreads();
      if (tid < 64) gpart[(((size_t)side*2 + b)*192 + h)*64 + tid] = sm.ep.gsum[tid];
    } else {
      #pragma unroll
      for (int mf = 0; mf < 4; ++mf)
        #pragma unroll
        for (int i = 0; i < 4; ++i) {
          int c = 64 + wm*64 + mf*16 + lg*4 + i;
          #pragma unroll
          for (int nf = 0; nf < 3; ++nf)
            V[((size_t)b*192 + c)*NN + h*192 + wn*48 + nf*16 + lr] = f2bf(acc[mf][nf][i]);
        }
    }
  }
}

// ---------------- repack v_h (ch 0..63 of V): [b][c][h][w] -> [b][c][w][h] ----------------
__global__ void k_repack_v(const ushort_t* __restrict__ Vl, const ushort_t* __restrict__ Vr,
                           ushort_t* __restrict__ vhTl, ushort_t* __restrict__ vhTr) {
  __shared__ ushort_t Ls[64*72];
  const ushort_t* V = blockIdx.y ? Vr : Vl;
  ushort_t* out = blockIdx.y ? vhTr : vhTl;
  int bx = blockIdx.x;                    // 1152 = 2b * 64c * 9 tiles
  int b = bx / 576, rem = bx % 576;
  int c = rem / 9, tt = rem % 9;
  int h0 = (tt/3)*64, w0 = (tt%3)*64;
  int tid = threadIdx.x;
  #pragma unroll
  for (int i = 0; i < 2; ++i) {
    int idx = tid + 256*i;
    int hh = idx >> 3, wb = idx & 7;
    *(u32x4*)&Ls[hh*72 + wb*8] =
      *(const u32x4*)&V[(size_t)(b*192 + c)*NN + (h0+hh)*192 + w0 + wb*8];
  }
  __syncthreads();
  #pragma unroll
  for (int i = 0; i < 2; ++i) {
    int idx = tid + 256*i;
    int ww = idx >> 3, hb = idx & 7;
    union { ushort_t us[8]; u32x4 v; } tu;
    #pragma unroll
    for (int j = 0; j < 8; ++j) tu.us[j] = Ls[(hb*8+j)*72 + ww];
    *(u32x4*)&out[(size_t)(b*64 + c)*NN + (w0+ww)*192 + h0 + hb*8] = tu.v;
  }
}

// ---------------- fused axial attention: LDS-P-free, 768 blocks, both modes ----------------
__global__ __launch_bounds__(256, 2) void k_attn(
    const ushort_t* __restrict__ qhTl, const ushort_t* __restrict__ qhTr,
    const ushort_t* __restrict__ qwTl, const ushort_t* __restrict__ qwTr,
    const ushort_t* __restrict__ Vl,  const ushort_t* __restrict__ Vr,
    const ushort_t* __restrict__ vhTl, const ushort_t* __restrict__ vhTr,
    const float* __restrict__ sch, const float* __restrict__ scw,
    ushort_t* __restrict__ Oh1, ushort_t* __restrict__ Oh2,
    ushort_t* __restrict__ Ow1, ushort_t* __restrict__ Ow2) {
  __shared__ ushort_t Qsl[192*64];   // swizzled [row][slot^row&7]
  __shared__ ushort_t Qsr[192*64];
  __shared__ ushort_t Vs[64*192];    // swizzled [c][slot^c&7]
  __shared__ float md[192*2];        // per-col (max, 1/den) from pass1

  const int tid = threadIdx.x;
  const int wave = tid >> 6, lane = tid & 63, lr = lane & 15, lg = lane >> 4;
  const int bx = blockIdx.x;
  const int mode = bx / 384;
  const int b = (bx % 384) / 192, s0 = bx % 192;
  const float scl = (mode ? scw : sch)[0];

  const ushort_t* ql = (mode ? qwTl : qhTl) + (size_t)(b*192 + s0)*12288;
  const ushort_t* qr = (mode ? qwTr : qhTr) + (size_t)(b*192 + s0)*12288;
  const ushort_t* vr = mode ? Vr + (size_t)(b*192 + 64)*NN + s0*192
                            : vhTr + (size_t)b*PL64 + s0*192;
  const ushort_t* vl = mode ? Vl + (size_t)(b*192 + 64)*NN + s0*192
                            : vhTl + (size_t)b*PL64 + s0*192;
  ushort_t* o1 = (mode ? Ow1 : Oh1) + (size_t)b*PL64 + s0*192;
  ushort_t* o2 = (mode ? Ow2 : Oh2) + (size_t)b*PL64 + s0*192;

  // ---- stage Q_l, Q_r, V_r (swizzled) ----
  #pragma unroll
  for (int i = 0; i < 6; ++i) {
    int idx = tid + 256*i;
    int r = idx >> 3, sl = idx & 7;
    int dq = r*64 + ((sl ^ (r & 7)) << 3);
    *(u32x4*)&Qsl[dq] = *(const u32x4*)&ql[idx*8];
    *(u32x4*)&Qsr[dq] = *(const u32x4*)&qr[idx*8];
    int c = idx / 24, gs = idx % 24;
    *(u32x4*)&Vs[c*192 + ((gs ^ (c & 7)) << 3)] = *(const u32x4*)&vr[(size_t)c*NN + gs*8];
  }
  __syncthreads();

  const f32x4 fz = {0.f, 0.f, 0.f, 0.f};
  f32x4 acc[12][3];
  unsigned pk[3][12][2];

  // QK^T: acc[row=mf*16+lg*4+i][col=wave*48+nf*16+lr]; swap=false: A=Qsr,B=Qsl
  auto qk = [&](bool swap) {
    const ushort_t* A  = swap ? Qsl : Qsr;
    const ushort_t* Bq = swap ? Qsr : Qsl;
    #pragma unroll
    for (int mf = 0; mf < 12; ++mf)
      #pragma unroll
      for (int nf = 0; nf < 3; ++nf) acc[mf][nf] = fz;
    #pragma unroll
    for (int kh = 0; kh < 2; ++kh) {
      bf16x8 bq[3];
      #pragma unroll
      for (int nf = 0; nf < 3; ++nf) {
        int r = wave*48 + nf*16 + lr;
        bq[nf] = lds8(&Bq[r*64 + (((kh*4 + lg) ^ (r & 7)) << 3)]);
      }
      #pragma unroll
      for (int mf = 0; mf < 12; ++mf) {
        int r = mf*16 + lr;
        bf16x8 aq = lds8(&A[r*64 + (((kh*4 + lg) ^ (r & 7)) << 3)]);
        #pragma unroll
        for (int nf = 0; nf < 3; ++nf) acc[mf][nf] = mfma16(aq, bq[nf], acc[mf][nf]);
      }
    }
  };

  // softmax over rows (lane-local mf/i + shfl over lg) + pack P to bf16 pairs
  auto smpack = [&](bool store_md) {
    #pragma unroll
    for (int nf = 0; nf < 3; ++nf) {
      float mx = -3.4e38f;
      #pragma unroll
      for (int mf = 0; mf < 12; ++mf)
        #pragma unroll
        for (int i = 0; i < 4; ++i) {
          float v = acc[mf][nf][i] * scl;
          acc[mf][nf][i] = v;
          mx = fmaxf(mx, v);
        }
      mx = fmaxf(mx, __shfl_xor(mx, 16));
      mx = fmaxf(mx, __shfl_xor(mx, 32));
      float den = 0.f;
      #pragma unroll
      for (int mf = 0; mf < 12; ++mf)
        #pragma unroll
        for (int i = 0; i < 4; ++i) {
          float e = __expf(acc[mf][nf][i] - mx);
          acc[mf][nf][i] = e;
          den += e;
        }
      den += __shfl_xor(den, 16);
      den += __shfl_xor(den, 32);
      float rd = 1.f / den;
      if (store_md && lg == 0) {
        int col = wave*48 + nf*16 + lr;
        md[col*2] = mx; md[col*2+1] = rd;
      }
      #pragma unroll
      for (int mf = 0; mf < 12; ++mf) {
        pk[nf][mf][0] = cvtpk(acc[mf][nf][0]*rd, acc[mf][nf][1]*rd);
        pk[nf][mf][1] = cvtpk(acc[mf][nf][2]*rd, acc[mf][nf][3]*rd);
      }
    }
  };

  // O[c=mf*16+lg*4+i][col] = sum_k P[k][col] * V[c][k]; B-frags via in-wave shfl
  auto pv = [&](ushort_t* op) {
    f32x4 o[4][3];
    #pragma unroll
    for (int mf = 0; mf < 4; ++mf)
      #pragma unroll
      for (int nf = 0; nf < 3; ++nf) o[mf][nf] = fz;
    const int sA = lr + 32*(lg & 1), sB = sA + 16;
    const bool hi = (lg >> 1) != 0;
    #pragma unroll
    for (int ks = 0; ks < 6; ++ks) {
      bf16x8 av[4];
      #pragma unroll
      for (int mf = 0; mf < 4; ++mf) {
        int c = mf*16 + lr;
        av[mf] = lds8(&Vs[c*192 + (((4*ks + lg) ^ (c & 7)) << 3)]);
      }
      #pragma unroll
      for (int nf = 0; nf < 3; ++nf) {
        unsigned w0a = (unsigned)__shfl((int)pk[nf][2*ks  ][0], sA);
        unsigned w0b = (unsigned)__shfl((int)pk[nf][2*ks+1][0], sA);
        unsigned w1a = (unsigned)__shfl((int)pk[nf][2*ks  ][1], sA);
        unsigned w1b = (unsigned)__shfl((int)pk[nf][2*ks+1][1], sA);
        unsigned w2a = (unsigned)__shfl((int)pk[nf][2*ks  ][0], sB);
        unsigned w2b = (unsigned)__shfl((int)pk[nf][2*ks+1][0], sB);
        unsigned w3a = (unsigned)__shfl((int)pk[nf][2*ks  ][1], sB);
        unsigned w3b = (unsigned)__shfl((int)pk[nf][2*ks+1][1], sB);
        u32x4 wv = { hi ? w0b : w0a, hi ? w1b : w1a, hi ? w2b : w2a, hi ? w3b : w3a };
        bf16x8 bp = __builtin_bit_cast(bf16x8, wv);
        #pragma unroll
        for (int mf = 0; mf < 4; ++mf) o[mf][nf] = mfma16(av[mf], bp, o[mf][nf]);
      }
    }
    #pragma unroll
    for (int mf = 0; mf < 4; ++mf)
      #pragma unroll
      for (int i = 0; i < 4; ++i)
        #pragma unroll
        for (int nf = 0; nf < 3; ++nf)
          op[(size_t)(mf*16 + lg*4 + i)*NN + wave*48 + nf*16 + lr] = f2bf(o[mf][nf][i]);
  };

  // ---- pass 1 ----
  qk(false);
  smpack(true);
  pv(o1);

  // prefetch V_l to regs (T14): issue before QK2, ds_write after barrier
  u32x4 vlr[6];
  #pragma unroll
  for (int i = 0; i < 6; ++i) {
    int idx = tid + 256*i;
    int c = idx / 24, gs = idx % 24;
    vlr[i] = *(const u32x4*)&vl[(size_t)c*NN + gs*8];
  }
  __syncthreads();                      // PV1 done everywhere; md visible

  // ---- pass 2 ----
  qk(true);
  #pragma unroll
  for (int i = 0; i < 6; ++i) {
    int idx = tid + 256*i;
    int c = idx / 24, gs = idx % 24;
    *(u32x4*)&Vs[c*192 + ((gs ^ (c & 7)) << 3)] = vlr[i];
  }
  if (mode == 0) {
    // H: P2[h][g] reuses pass1 stats keyed by row h
    #pragma unroll
    for (int mf = 0; mf < 12; ++mf)
      #pragma unroll
      for (int i = 0; i < 4; ++i) {
        int row = mf*16 + lg*4 + i;
        float m_ = md[row*2], rd_ = md[row*2+1];
        #pragma unroll
        for (int nf = 0; nf < 3; ++nf)
          acc[mf][nf][i] = __expf(acc[mf][nf][i]*scl - m_) * rd_;
      }
    #pragma unroll
    for (int nf = 0; nf < 3; ++nf)
      #pragma unroll
      for (int mf = 0; mf < 12; ++mf) {
        pk[nf][mf][0] = cvtpk(acc[mf][nf][0], acc[mf][nf][1]);
        pk[nf][mf][1] = cvtpk(acc[mf][nf][2], acc[mf][nf][3]);
      }
  } else {
    // W: independent second softmax over rows
    smpack(false);
  }
  __syncthreads();                      // V_l writes visible
  pv(o2);
}

// ---------------- SE: reduce gpart + MLP ----------------
__global__ void k_se(const float* __restrict__ gpart, const float* __restrict__ w1,
                     const float* __restrict__ w2, float* __restrict__ sea) {
  __shared__ float p[2][64];
  __shared__ float h1[2][8];
  __shared__ float lgt[2][128];
  __shared__ float mred[2], dred[2];
  int t = threadIdx.x;
  if (t < 128) {
    int b = t >> 6, c = t & 63;
    float s = 0.f;
    for (int side = 0; side < 2; ++side)
      for (int h = 0; h < 192; ++h)
        s += gpart[(((size_t)side*2 + b)*192 + h)*64 + c];
    p[b][c] = s * (1.f/36864.f);
  }
  __syncthreads();
  if (t < 16) {
    int bb = t >> 3, j = t & 7;
    float s = 0.f;
    for (int k = 0; k < 64; ++k) s += p[bb][k] * w1[j*64 + k];
    h1[bb][j] = fmaxf(s, 0.f);
  }
  __syncthreads();
  {
    int bb = t >> 7, o = t & 127;
    float s = 0.f;
    #pragma unroll
    for (int j = 0; j < 8; ++j) s += h1[bb][j] * w2[o*8 + j];
    lgt[bb][o] = s;
  }
  __syncthreads();
  if (t < 2) {
    float mx = -3.4e38f;
    for (int o = 0; o < 128; ++o) mx = fmaxf(mx, lgt[t][o]);
    float d = 0.f;
    for (int o = 0; o < 128; ++o) d += __expf(lgt[t][o] - mx);
    mred[t] = mx; dred[t] = d;
  }
  __syncthreads();
  {
    int bb = t >> 7, o = t & 127;
    sea[bb*128 + o] = __expf(lgt[bb][o] - mred[bb]) / dred[bb];
  }
}

// ---------------- epilogue: h-channels (transpose back) ----------------
__global__ void k_ep_h(const ushort_t* __restrict__ Oh1, const ushort_t* __restrict__ Oh2,
                       const float* __restrict__ xl, const float* __restrict__ xr,
                       const float* __restrict__ ls1, const float* __restrict__ ls2,
                       float* __restrict__ out) {
  __shared__ ushort_t Ls[64*72];
  int dir = blockIdx.y;
  const ushort_t* O = dir ? Oh2 : Oh1;
  const float* xin = dir ? xr : xl;
  float lsv = (dir ? ls2 : ls1)[blockIdx.x % 576 / 9];
  int bx = blockIdx.x;                    // 1152 = 2b * 64c * 9 tiles
  int b = bx / 576, rem = bx % 576;
  int c = rem / 9, tt = rem % 9;
  int h0 = (tt/3)*64, w0 = (tt%3)*64;
  int tid = threadIdx.x;
  const ushort_t* Ob = O + (size_t)(b*64 + c)*NN;
  const float* xb = xin + (size_t)(b*192 + c)*NN;
  float* ob = out + (size_t)dir*TOT + (size_t)(b*192 + c)*NN;
  #pragma unroll
  for (int i = 0; i < 2; ++i) {
    int idx = tid + 256*i;
    int ww = idx >> 3, hb = idx & 7;
    *(u32x4*)&Ls[ww*72 + hb*8] = *(const u32x4*)&Ob[(w0+ww)*192 + h0 + hb*8];
  }
  __syncthreads();
  #pragma unroll
  for (int i = 0; i < 2; ++i) {
    int idx = tid + 256*i;
    int hh = idx >> 3, wb = idx & 7;
    int base = (h0+hh)*192 + w0 + wb*8;
    f32x4 xa = *(const f32x4*)&xb[base];
    f32x4 xc = *(const f32x4*)&xb[base + 4];
    f32x4 r0, r1;
    #pragma unroll
    for (int j = 0; j < 4; ++j) r0[j] = bf2f(Ls[(wb*8+j)*72 + hh])*lsv + xa[j];
    #pragma unroll
    for (int j = 0; j < 4; ++j) r1[j] = bf2f(Ls[(wb*8+4+j)*72 + hh])*lsv + xc[j];
    *(f32x4*)&ob[base] = r0;
    *(f32x4*)&ob[base + 4] = r1;
  }
}

// ---------------- epilogue: w-channels + SE channels (elementwise) ----------------
__global__ void k_ep_wc(const ushort_t* __restrict__ Ow1, const ushort_t* __restrict__ Ow2,
                        const ushort_t* __restrict__ Vl, const ushort_t* __restrict__ Vr,
                        const float* __restrict__ sea,
                        const float* __restrict__ xl, const float* __restrict__ xr,
                        const float* __restrict__ ls1, const float* __restrict__ ls2,
                        float* __restrict__ out) {
  int gid = blockIdx.x;                   // 9216 = 2dir * 2b * 128c * 18 tiles
  int tile = gid % 18;
  int c128 = (gid / 18) % 128;
  int b = (gid / (18*128)) % 2;
  int dir = gid / (18*128*2);
  int cg = 64 + c128;
  const float* xin = dir ? xr : xl;
  float lsv = (dir ? ls2 : ls1)[cg];
  int n0 = tile*2048 + threadIdx.x*8;
  size_t xo = (size_t)(b*192 + cg)*NN + n0;
  const ushort_t* src;
  float mult;
  if (c128 < 64) {
    src = (dir ? Ow2 : Ow1) + (size_t)(b*64 + c128)*NN + n0;
    mult = lsv;
  } else {
    int cc = c128 - 64;
    src = (dir ? Vr : Vl) + (size_t)(b*192 + 128 + cc)*NN + n0;
    mult = lsv * sea[b*128 + dir*64 + cc];
  }
  u32x4 sv = *(const u32x4*)src;
  const ushort_t* sp = (const ushort_t*)&sv;
  f32x4 xa = *(const f32x4*)&xin[xo];
  f32x4 xb = *(const f32x4*)&xin[xo + 4];
  f32x4 r0, r1;
  #pragma unroll
  for (int j = 0; j < 4; ++j) r0[j] = bf2f(sp[j])*mult + xa[j];
  #pragma unroll
  for (int j = 0; j < 4; ++j) r1[j] = bf2f(sp[4+j])*mult + xb[j];
  float* ob = out + (size_t)dir*TOT;
  *(f32x4*)&ob[xo] = r0;
  *(f32x4*)&ob[xo + 4] = r1;
}

extern "C" void kernel_launch(void* const* d_in, const int* in_sizes, int n_in,
                              void* d_out, int out_size, void* d_ws, size_t ws_size,
                              hipStream_t stream) {
  const float* x_l  = (const float*)d_in[0];
  const float* x_r  = (const float*)d_in[1];
  const float* lnlw = (const float*)d_in[2];
  const float* lnlb = (const float*)d_in[3];
  const float* lnrw = (const float*)d_in[4];
  const float* lnrb = (const float*)d_in[5];
  const float* wq_l = (const float*)d_in[6];
  const float* wq_r = (const float*)d_in[7];
  const float* wv_l = (const float*)d_in[8];
  const float* wv_r = (const float*)d_in[9];
  const float* w1   = (const float*)d_in[10];
  const float* w2   = (const float*)d_in[11];
  const float* sch  = (const float*)d_in[12];
  const float* scw  = (const float*)d_in[13];
  const float* ls1  = (const float*)d_in[14];
  const float* ls2  = (const float*)d_in[15];
  float* out = (float*)d_out;

  char* ws = (char*)d_ws;
  size_t off = 0;
  auto alloc = [&](size_t bytes) {
    char* p = ws + off;
    off += (bytes + 255) & ~(size_t)255;
    return p;
  };
  ushort_t* Vl   = (ushort_t*)alloc((size_t)2*192*NN*2);
  ushort_t* Vr   = (ushort_t*)alloc((size_t)2*192*NN*2);
  ushort_t* qhTl = (ushort_t*)alloc((size_t)2*64*NN*2);
  ushort_t* qhTr = (ushort_t*)alloc((size_t)2*64*NN*2);
  ushort_t* qwTl = (ushort_t*)alloc((size_t)2*64*NN*2);
  ushort_t* qwTr = (ushort_t*)alloc((size_t)2*64*NN*2);
  ushort_t* vhTl = (ushort_t*)alloc((size_t)2*64*NN*2);
  ushort_t* vhTr = (ushort_t*)alloc((size_t)2*64*NN*2);
  ushort_t* Oh1  = (ushort_t*)alloc((size_t)2*64*NN*2);
  ushort_t* Oh2  = (ushort_t*)alloc((size_t)2*64*NN*2);
  ushort_t* Ow1  = (ushort_t*)alloc((size_t)2*64*NN*2);
  ushort_t* Ow2  = (ushort_t*)alloc((size_t)2*64*NN*2);
  ushort_t* Wl   = (ushort_t*)alloc((size_t)384*192*2);
  ushort_t* Wr   = (ushort_t*)alloc((size_t)384*192*2);
  float* abl = (float*)alloc(384*4);
  float* abr = (float*)alloc(384*4);
  float* stl = (float*)alloc((size_t)4*NN*4);
  float* str = (float*)alloc((size_t)4*NN*4);
  float* gpart = (float*)alloc((size_t)2*2*192*64*4);
  float* sea = (float*)alloc(2*128*4);
  (void)in_sizes; (void)n_in; (void)out_size; (void)ws_size;

  k_prep<<<384, 192, 0, stream>>>(wq_l, wv_l, lnlw, lnlb, Wl, abl);
  k_prep<<<384, 192, 0, stream>>>(wq_r, wv_r, lnrw, lnrb, Wr, abr);
  k_stats<<<576, 256, 0, stream>>>(x_l, x_r, stl, str);
  k_proj<<<dim3(1152, 2), 512, 0, stream>>>(x_l, x_r, Wl, Wr, abl, abr, stl, str,
                                            qhTl, qhTr, qwTl, qwTr, Vl, Vr, gpart);
  k_repack_v<<<dim3(1152, 2), 256, 0, stream>>>(Vl, Vr, vhTl, vhTr);
  k_attn<<<768, 256, 0, stream>>>(qhTl, qhTr, qwTl, qwTr, Vl, Vr, vhTl, vhTr,
                                  sch, scw, Oh1, Oh2, Ow1, Ow2);
  k_se<<<1, 256, 0, stream>>>(gpart, w1, w2, sea);
  k_ep_h<<<dim3(1152, 2), 256, 0, stream>>>(Oh1, Oh2, x_l, x_r, ls1, ls2, out);
  k_ep_wc<<<9216, 256, 0, stream>>>(Ow1, Ow2, Vl, Vr, sea, x_l, x_r, ls1, ls2, out);
}